// Round 1
// baseline (2565.903 us; speedup 1.0000x reference)
//
#include <hip/hip_runtime.h>

// ---------------- constants ----------------
#define NN 2048
#define EE 262144

typedef __attribute__((ext_vector_type(8))) short bf16x8;
typedef __attribute__((ext_vector_type(4))) float f32x4;
typedef unsigned int u32;
typedef unsigned short u16;

__device__ __forceinline__ u16 f2bf(float f){
  u32 u = __builtin_bit_cast(u32, f);
  u32 r = u + 0x7FFFu + ((u >> 16) & 1u);
  return (u16)(r >> 16);
}
__device__ __forceinline__ float bf2f(u16 h){
  u32 u = ((u32)h) << 16;
  return __builtin_bit_cast(float, u);
}
__device__ __forceinline__ int swzb(int byte, int row){ return byte ^ ((row & 7) << 4); }
__device__ __forceinline__ float lrelu(float v){ return v > 0.f ? v : 0.01f * v; }

// ---------------- ws layout (bytes) ----------------
static const size_t WS_WT    = 0;                    // u16 pool, 386048 elems (772096 B)
static const size_t WS_EFNN  = 772096;               // u16 E*64
static const size_t WS_ALPHA = WS_EFNN  + 33554432;  // f32 2E  (a_dir | a_rev)
static const size_t WS_H     = WS_ALPHA + 2097152;   // f32 N*96
static const size_t WS_QKV   = WS_H     + 786432;    // f32 N*288
static const size_t WS_OBUF  = WS_QKV   + 2359296;   // f32 N*96
static const size_t WS_TMPA  = WS_OBUF  + 786432;    // f32 N*96
static const size_t WS_TMPB  = WS_TMPA  + 786432;    // f32 N*192
static const size_t WS_X1    = WS_TMPB  + 1572864;   // f32 N*96
static const size_t WS_NUM   = WS_X1    + 786432;    // f32 N*96
static const size_t WS_DEN   = WS_NUM   + 786432;    // f32 N (pad)
static const size_t WS_XS    = WS_DEN   + 8192;      // f32 N*19

// pool element offsets (bf16, weights transposed [Nc][Kpad])
#define IN1T 0
#define IN2T 3072
#define QKVT 12288
#define OUTT 95232
#define FF1T 122880
#define FF2T 178176
#define EIN1T 233472
#define EIN2T 235520
#define AD1T 239616
#define AR1T 243712
#define GC1T 247808
#define GC2T 321536
#define EN1T 358400
#define POOL_TOT 386048

// ---------------- weight convert (f32 -> bf16, transposed, K-padded) ----------------
struct CvtJobs {
  const float* src[23];
  int K[23], Nc[23], Kp[23];
  int cum[24];
};

__global__ __launch_bounds__(256) void k_cvt(CvtJobs jb, u16* __restrict__ pool){
  int i = blockIdx.x * 256 + threadIdx.x;
  if (i >= jb.cum[23]) return;
  int j = 0;
  while (i >= jb.cum[j + 1]) j++;
  int loc = i - jb.cum[j];
  int Kp = jb.Kp[j];
  int n = loc / Kp, k = loc - n * Kp;
  float v = (k < jb.K[j]) ? jb.src[j][(size_t)k * jb.Nc[j] + n] : 0.f;
  pool[i] = f2bf(v);
}

__global__ __launch_bounds__(256) void k_xscale(const float* __restrict__ X, const float* __restrict__ ns,
                                                float* __restrict__ xs){
  int i = blockIdx.x * 256 + threadIdx.x;
  if (i < NN * 19) xs[i] = X[i] / ns[i % 19];
}

// ---------------- MFMA tile helper ----------------
// A in LDS [rows][SR bytes], swizzled; B (W^T) in LDS [Nc][SR bytes], swizzled.
// frag layouts (16x16x32 bf16): A lane l -> row l&15, k (l>>4)*8+j ; D: row=(l>>4)*4+q, col=l&15
template<int NT, int KS, int SR>
__device__ __forceinline__ void tile_gemm(const char* sm, int aBase, int bBase, int lane, f32x4* acc){
  const int r15 = lane & 15;
  const int kb = (lane >> 4) * 16;
  #pragma unroll
  for (int ks = 0; ks < KS; ks++){
    bf16x8 a = *(const bf16x8*)(sm + aBase + swzb(r15*SR + ks*64 + kb, r15));
    #pragma unroll
    for (int ct = 0; ct < NT; ct++){
      int n = ct*16 + r15;
      bf16x8 b = *(const bf16x8*)(sm + bBase + swzb(n*SR + ks*64 + kb, n));
      acc[ct] = __builtin_amdgcn_mfma_f32_16x16x32_bf16(a, b, acc[ct], 0, 0, 0);
    }
  }
}

// ---------------- generic GEMM: C[M][Nc] = act(A[M][K] @ W + bias), M mult of 64 ----------------
template<int NT, int KS, int ACT>
__global__ __launch_bounds__(256) void k_gemm(const float* __restrict__ A, int K,
    const u16* __restrict__ Wt, const float* __restrict__ bias, float* __restrict__ C)
{
  constexpr int Kpad = KS * 32;
  constexpr int Nc = NT * 16;
  constexpr int SR = (Kpad*2 + 127) / 128 * 128;
  constexpr int ABASE = Nc * SR;
  __shared__ __align__(16) char smem[Nc*SR + 64*SR];
  constexpr int KP8 = Kpad / 8;
  for (int j = threadIdx.x; j < Nc*KP8; j += 256){
    int n = j / KP8;
    *(uint4*)(smem + swzb(n*SR + (j - n*KP8)*16, n)) = ((const uint4*)Wt)[j];
  }
  const int row0 = blockIdx.x * 64;
  for (int j = threadIdx.x; j < 64*(Kpad/2); j += 256){
    int r = j / (Kpad/2); int c = (j - r*(Kpad/2)) * 2;
    const float* ap = A + (size_t)(row0 + r)*K + c;
    float f0 = (c < K) ? ap[0] : 0.f;
    float f1 = (c + 1 < K) ? ap[1] : 0.f;
    *(u32*)(smem + ABASE + swzb(r*SR + c*2, r)) = (u32)f2bf(f0) | ((u32)f2bf(f1) << 16);
  }
  __syncthreads();
  const int lane = threadIdx.x & 63, w = threadIdx.x >> 6;
  const int r15 = lane & 15;
  f32x4 acc[NT] = {};
  tile_gemm<NT, KS, SR>(smem, ABASE + w*16*SR, 0, lane, acc);
  #pragma unroll
  for (int ct = 0; ct < NT; ct++){
    int col = ct*16 + r15;
    float bs = bias[col];
    #pragma unroll
    for (int q = 0; q < 4; q++){
      int r = row0 + w*16 + (lane >> 4)*4 + q;
      float v = acc[ct][q] + bs;
      if (ACT == 1) v = lrelu(v);
      if (ACT == 2) v = v > 0.f ? v : 0.f;
      C[(size_t)r*Nc + col] = v;
    }
  }
}

// ---------------- LayerNorm(a+b) ----------------
__global__ __launch_bounds__(256) void k_ln(const float* __restrict__ A, const float* __restrict__ B,
    const float* __restrict__ sc, const float* __restrict__ bi, float* __restrict__ out)
{
  const int row = blockIdx.x*4 + (threadIdx.x >> 6);
  const int lane = threadIdx.x & 63;
  const float* ap = A + row*96; const float* bp = B + row*96;
  float v1 = ap[lane] + bp[lane];
  float v2 = (lane < 32) ? (ap[64+lane] + bp[64+lane]) : 0.f;
  float sum = v1 + v2, sq = v1*v1 + v2*v2;
  #pragma unroll
  for (int st = 1; st < 64; st <<= 1){ sum += __shfl_xor(sum, st); sq += __shfl_xor(sq, st); }
  float mean = sum * (1.f/96.f);
  float var = sq * (1.f/96.f) - mean*mean;
  float rs = rsqrtf(var + 1e-5f);
  out[row*96 + lane] = (v1 - mean)*rs*sc[lane] + bi[lane];
  if (lane < 32) out[row*96 + 64 + lane] = (v2 - mean)*rs*sc[64+lane] + bi[64+lane];
}

// ---------------- fused flash-style attention (fp32), one (head, 64-row) block ----------------
__global__ __launch_bounds__(256) void k_attn(const float* __restrict__ qkv, float* __restrict__ obuf){
  __shared__ float KV[2][2048*9];   // [isV][m*9+d], stride 9 kills bank conflicts
  const int tid = threadIdx.x;
  const int head = blockIdx.x >> 5, rb = blockIdx.x & 31;
  for (int fl = tid; fl < 32768; fl += 256){
    int m = fl >> 4, idx = fl & 15, isV = idx >> 3, d = idx & 7;
    KV[isV][m*9 + d] = qkv[m*288 + 96 + isV*96 + head*8 + d];
  }
  __syncthreads();
  const int lane = tid & 63, w = tid >> 6;
  for (int rr = 0; rr < 16; rr++){
    int row = rb*64 + w*16 + rr;
    const float* qp = qkv + (size_t)row*288 + head*8;
    float q0=qp[0],q1=qp[1],q2=qp[2],q3=qp[3],q4=qp[4],q5=qp[5],q6=qp[6],q7=qp[7];
    float mx = -1e30f, sm = 0.f;
    float o[8] = {0,0,0,0,0,0,0,0};
    for (int j = 0; j < 32; j++){
      int m = lane + 64*j;
      const float* kp = &KV[0][m*9];
      float s = q0*kp[0]+q1*kp[1]+q2*kp[2]+q3*kp[3]+q4*kp[4]+q5*kp[5]+q6*kp[6]+q7*kp[7];
      s *= 0.35355339059327373f;  // 1/sqrt(8)
      const float* vp = &KV[1][m*9];
      if (s <= mx){
        float p = __expf(s - mx);
        sm += p;
        #pragma unroll
        for (int d = 0; d < 8; d++) o[d] += p * vp[d];
      } else {
        float scl = __expf(mx - s);
        sm = sm*scl + 1.f;
        #pragma unroll
        for (int d = 0; d < 8; d++) o[d] = o[d]*scl + vp[d];
        mx = s;
      }
    }
    #pragma unroll
    for (int st = 1; st < 64; st <<= 1){
      float omx = __shfl_xor(mx, st);
      float osm = __shfl_xor(sm, st);
      float nm = fmaxf(mx, omx);
      float ea = __expf(mx - nm), eb = __expf(omx - nm);
      #pragma unroll
      for (int d = 0; d < 8; d++){
        float od = __shfl_xor(o[d], st);
        o[d] = o[d]*ea + od*eb;
      }
      sm = sm*ea + osm*eb;
      mx = nm;
    }
    if (lane == 0){
      float inv = 1.f / sm;
      float* op = obuf + (size_t)row*96 + head*8;
      #pragma unroll
      for (int d = 0; d < 8; d++) op[d] = o[d]*inv;
    }
  }
}

// ---------------- fused edge MLPs: ef -> ein1 -> ein2 (efnn) -> {ad, ar} -> alpha ----------------
__global__ __launch_bounds__(256) void k_edge(const float* __restrict__ efr, const float* __restrict__ es,
    const u16* __restrict__ pool,
    const float* __restrict__ eb1, const float* __restrict__ eb2,
    const float* __restrict__ adb1, const float* __restrict__ adw2, const float* __restrict__ adb2,
    const float* __restrict__ arb1, const float* __restrict__ arw2, const float* __restrict__ arb2,
    u16* __restrict__ efnn, float* __restrict__ alpha)
{
  // LDS: [0)Wein1 [8192)Wein2 [16384)Wad1 [24576)War1 [32768)bufA [40960)bufB, all [64 rows][128B]
  __shared__ __align__(16) char smem[49152];
  const int tid = threadIdx.x;
  const int e0 = blockIdx.x * 64;
  for (int j = tid; j < 256; j += 256){
    int n = j >> 2;
    *(uint4*)(smem + swzb(n*128 + (j&3)*16, n)) = ((const uint4*)(pool + EIN1T))[j];
  }
  for (int j = tid; j < 512; j += 256){
    int n = j >> 3; int b = n*128 + (j&7)*16;
    *(uint4*)(smem + 8192  + swzb(b, n)) = ((const uint4*)(pool + EIN2T))[j];
    *(uint4*)(smem + 16384 + swzb(b, n)) = ((const uint4*)(pool + AD1T))[j];
    *(uint4*)(smem + 24576 + swzb(b, n)) = ((const uint4*)(pool + AR1T))[j];
  }
  for (int j = tid; j < 64*16; j += 256){
    int r = j >> 4; int c = (j & 15) * 2;
    float f0 = 0.f, f1 = 0.f;
    if (c < 12)     f0 = (efr[(e0+r)*12 + c]     + 1e-4f) / es[c];
    if (c + 1 < 12) f1 = (efr[(e0+r)*12 + c + 1] + 1e-4f) / es[c+1];
    *(u32*)(smem + 32768 + swzb(r*128 + c*2, r)) = (u32)f2bf(f0) | ((u32)f2bf(f1) << 16);
  }
  __syncthreads();
  const int lane = tid & 63, w = tid >> 6;
  const int r15 = lane & 15;

  auto store_lds = [&](f32x4* acc, int base, const float* bias){
    #pragma unroll
    for (int ct = 0; ct < 4; ct++){
      int col = ct*16 + r15;
      float bs = bias[col];
      #pragma unroll
      for (int q = 0; q < 4; q++){
        int row = w*16 + (lane >> 4)*4 + q;
        *(u16*)(smem + base + swzb(row*128 + col*2, row)) = f2bf(lrelu(acc[ct][q] + bs));
      }
    }
  };

  { f32x4 acc[4] = {};
    tile_gemm<4,1,128>(smem, 32768 + w*2048, 0, lane, acc);
    store_lds(acc, 40960, eb1); }                    // h1 -> bufB
  { f32x4 acc[4] = {};
    tile_gemm<4,2,128>(smem, 40960 + w*2048, 8192, lane, acc);
    store_lds(acc, 32768, eb2); }                    // efnn -> bufA (overwrites ef)
  __syncthreads();
  for (int j = tid; j < 2048; j += 256){             // coalesced efnn store (bf16)
    int r = j >> 5;
    ((u32*)efnn)[e0*32 + j] = *(const u32*)(smem + 32768 + swzb(r*128 + (j&31)*4, r));
  }
  { f32x4 acc[4] = {};
    tile_gemm<4,2,128>(smem, 32768 + w*2048, 16384, lane, acc);
    store_lds(acc, 40960, adb1); }                   // t_dir -> bufB
  __syncthreads();
  { int row = tid >> 2, part = tid & 3;
    float s = 0.f;
    #pragma unroll
    for (int i = 0; i < 16; i++){
      int k = part*16 + i;
      s += bf2f(*(const u16*)(smem + 40960 + swzb(row*128 + k*2, row))) * adw2[k];
    }
    s += __shfl_xor(s, 1); s += __shfl_xor(s, 2);
    if (part == 0) alpha[e0 + row] = 1.f / (1.f + __expf(-(s + adb2[0]))); }
  __syncthreads();
  { f32x4 acc[4] = {};
    tile_gemm<4,2,128>(smem, 32768 + w*2048, 24576, lane, acc);
    store_lds(acc, 40960, arb1); }                   // t_rev -> bufB
  __syncthreads();
  { int row = tid >> 2, part = tid & 3;
    float s = 0.f;
    #pragma unroll
    for (int i = 0; i < 16; i++){
      int k = part*16 + i;
      s += bf2f(*(const u16*)(smem + 40960 + swzb(row*128 + k*2, row))) * arw2[k];
    }
    s += __shfl_xor(s, 1); s += __shfl_xor(s, 2);
    if (part == 0) alpha[EE + e0 + row] = 1.f / (1.f + __expf(-(s + arb2[0]))); }
}

// ---------------- fused graph-conv over the 2E edge rows (gather -> MLP -> atomic scatter) ----------------
__global__ __launch_bounds__(256) void k_gc(const float* __restrict__ h, const int* __restrict__ ei,
    const float* __restrict__ alpha, const u16* __restrict__ wt1, const u16* __restrict__ wt2,
    const float* __restrict__ b1, const float* __restrict__ b2, float* __restrict__ num)
{
  // LDS: [0,73728) Wt1 [192][384B] swz ; [73728,122880) bufA [128][384B] swz
  __shared__ __align__(16) char smem[122880];
  const int tid = threadIdx.x;
  const int row0 = blockIdx.x * 128;
  for (int j = tid; j < 4608; j += 256){
    int n = j / 24;
    *(uint4*)(smem + swzb(n*384 + (j - n*24)*16, n)) = ((const uint4*)wt1)[j];
  }
  for (int j = tid; j < 12288; j += 256){
    int r = j / 96; int c = (j - r*96) * 2;
    int g = row0 + r;
    int i1, i2;
    if (g < EE){ i1 = ei[2*g]; i2 = ei[2*g+1]; }
    else { int gg = g - EE; i1 = ei[2*gg+1]; i2 = ei[2*gg]; }
    int sr = (c < 96) ? i1 : i2;
    int cc = (c < 96) ? c : c - 96;
    const float* hp = h + sr*96 + cc;
    *(u32*)(smem + 73728 + swzb(r*384 + c*2, r)) = (u32)f2bf(hp[0]) | ((u32)f2bf(hp[1]) << 16);
  }
  __syncthreads();
  const int lane = tid & 63, w = tid >> 6;
  const int wr = w >> 1, wc = w & 1;           // 2x2 wave grid: 64 rows x 96 cols each
  const int r15 = lane & 15, kb = (lane >> 4) * 16;
  f32x4 acc[4][6] = {};
  #pragma unroll
  for (int ks = 0; ks < 6; ks++){
    bf16x8 a[4];
    #pragma unroll
    for (int rt = 0; rt < 4; rt++){
      int row = wr*64 + rt*16 + r15;
      a[rt] = *(const bf16x8*)(smem + 73728 + swzb(row*384 + ks*64 + kb, row));
    }
    #pragma unroll
    for (int ct = 0; ct < 6; ct++){
      int n = wc*96 + ct*16 + r15;
      bf16x8 b = *(const bf16x8*)(smem + swzb(n*384 + ks*64 + kb, n));
      #pragma unroll
      for (int rt = 0; rt < 4; rt++)
        acc[rt][ct] = __builtin_amdgcn_mfma_f32_16x16x32_bf16(a[rt], b, acc[rt][ct], 0, 0, 0);
    }
  }
  __syncthreads();
  #pragma unroll
  for (int ct = 0; ct < 6; ct++){
    int col = wc*96 + ct*16 + r15;
    float bs = b1[col];
    #pragma unroll
    for (int rt = 0; rt < 4; rt++){
      #pragma unroll
      for (int q = 0; q < 4; q++){
        int row = wr*64 + rt*16 + (lane >> 4)*4 + q;
        *(u16*)(smem + 73728 + swzb(row*384 + col*2, row)) = f2bf(lrelu(acc[rt][ct][q] + bs));
      }
    }
  }
  __syncthreads();
  f32x4 acc2[4][3] = {};
  #pragma unroll
  for (int ks = 0; ks < 6; ks++){
    bf16x8 a[4];
    #pragma unroll
    for (int rt = 0; rt < 4; rt++){
      int row = wr*64 + rt*16 + r15;
      a[rt] = *(const bf16x8*)(smem + 73728 + swzb(row*384 + ks*64 + kb, row));
    }
    #pragma unroll
    for (int ct = 0; ct < 3; ct++){
      int n = wc*48 + ct*16 + r15;
      bf16x8 b = *(const bf16x8*)((const char*)wt2 + n*384 + ks*64 + kb);   // L2-hot global
      #pragma unroll
      for (int rt = 0; rt < 4; rt++)
        acc2[rt][ct] = __builtin_amdgcn_mfma_f32_16x16x32_bf16(a[rt], b, acc2[rt][ct], 0, 0, 0);
    }
  }
  #pragma unroll
  for (int ct = 0; ct < 3; ct++){
    int col = wc*48 + ct*16 + r15;
    float bs = b2[col];
    #pragma unroll
    for (int rt = 0; rt < 4; rt++){
      #pragma unroll
      for (int q = 0; q < 4; q++){
        int g = row0 + wr*64 + rt*16 + (lane >> 4)*4 + q;
        float v = lrelu(acc2[rt][ct][q] + bs);
        int i1 = (g < EE) ? ei[2*g] : ei[2*(g - EE) + 1];
        atomicAdd(num + i1*96 + col, alpha[g] * v);
      }
    }
  }
}

// the N rows with ind1=ind2=0 are identical: compute once, add 2048x
__global__ __launch_bounds__(256) void k_gcnode0(const float* __restrict__ h,
    const float* __restrict__ W1, const float* __restrict__ b1,
    const float* __restrict__ W2, const float* __restrict__ b2, float* __restrict__ num)
{
  __shared__ float in_s[192], h1_s[192];
  int t = threadIdx.x;
  if (t < 192) in_s[t] = h[t % 96];
  __syncthreads();
  if (t < 192){
    float s = b1[t];
    for (int k = 0; k < 192; k++) s += in_s[k] * W1[k*192 + t];
    h1_s[t] = lrelu(s);
  }
  __syncthreads();
  if (t < 96){
    float s = b2[t];
    for (int k = 0; k < 192; k++) s += h1_s[k] * W2[k*96 + t];
    num[t] += 2048.f * lrelu(s);
  }
}

__global__ __launch_bounds__(256) void k_den(const int* __restrict__ ei, const float* __restrict__ alpha,
                                             float* __restrict__ den){
  int g = blockIdx.x * 256 + threadIdx.x;  // 2E rows
  int i1 = (g < EE) ? ei[2*g] : ei[2*(g - EE) + 1];
  atomicAdd(den + i1, alpha[g]);
  if (g == 0) atomicAdd(den, 2048.f);
}

__global__ __launch_bounds__(256) void k_hupd(const float* __restrict__ num, const float* __restrict__ den,
                                              float* __restrict__ h){
  int i = blockIdx.x * 256 + threadIdx.x;  // N*96
  h[i] = num[i] / (den[i / 96] + 1e-8f);
}

// ---------------- final per-edge predictor ----------------
__global__ __launch_bounds__(256) void k_final(const float* __restrict__ h, const int* __restrict__ ei,
    const u16* __restrict__ efnn, const float* __restrict__ efr, const float* __restrict__ es,
    const u16* __restrict__ en1, const float* __restrict__ enb1,
    const float* __restrict__ enw2, const float* __restrict__ enb2, float* __restrict__ out)
{
  // LDS: [0,61440) Wen1 [96][640B] swz ; [61440,102400) bufA [64][640B] swz ; [102400,..) bufB f32 [64][97]
  __shared__ __align__(16) char smem[127232];
  const int tid = threadIdx.x;
  const int e0 = blockIdx.x * 64;
  for (int j = tid; j < 3456; j += 256){
    int n = j / 36;
    *(uint4*)(smem + swzb(n*640 + (j - n*36)*16, n)) = ((const uint4*)en1)[j];
  }
  for (int j = tid; j < 9216; j += 256){
    int r = j / 144; int c = (j - r*144) * 2;
    int e = e0 + r;
    u32 pk;
    if (c < 192){
      int idx = (c < 96) ? ei[2*e] : ei[2*e + 1];
      int cc = (c < 96) ? c : c - 96;
      const float* hp = h + idx*96 + cc;
      pk = (u32)f2bf(hp[0]) | ((u32)f2bf(hp[1]) << 16);
    } else if (c < 256){
      pk = ((const u32*)efnn)[(e*64 + (c - 192)) >> 1];
    } else {
      int cc = c - 256;
      float f0 = (cc < 12)     ? (efr[e*12 + cc]     + 1e-4f) / es[cc]   : 0.f;
      float f1 = (cc + 1 < 12) ? (efr[e*12 + cc + 1] + 1e-4f) / es[cc+1] : 0.f;
      pk = (u32)f2bf(f0) | ((u32)f2bf(f1) << 16);
    }
    *(u32*)(smem + 61440 + swzb(r*640 + c*2, r)) = pk;
  }
  __syncthreads();
  const int lane = tid & 63, w = tid >> 6;
  const int r15 = lane & 15;
  f32x4 acc[6] = {};
  tile_gemm<6,9,640>(smem, 61440 + w*10240, 0, lane, acc);
  #pragma unroll
  for (int ct = 0; ct < 6; ct++){
    int col = ct*16 + r15;
    float bs = enb1[col];
    #pragma unroll
    for (int q = 0; q < 4; q++){
      int row = w*16 + (lane >> 4)*4 + q;
      *(float*)(smem + 102400 + (row*97 + col)*4) = lrelu(acc[ct][q] + bs);
    }
  }
  __syncthreads();
  int row = tid >> 2, part = tid & 3;
  float s = 0.f;
  #pragma unroll
  for (int i = 0; i < 24; i++){
    int k = part*24 + i;
    s += *(const float*)(smem + 102400 + (row*97 + k)*4) * enw2[k];
  }
  s += __shfl_xor(s, 1); s += __shfl_xor(s, 2);
  if (part == 0) out[e0 + row] = 1.f / (1.f + __expf(-(s + enb2[0])));
}

// ---------------- host ----------------
extern "C" void kernel_launch(void* const* d_in, const int* in_sizes, int n_in,
                              void* d_out, int out_size, void* d_ws, size_t ws_size,
                              hipStream_t stream) {
  (void)in_sizes; (void)n_in; (void)out_size; (void)ws_size;
  const float* X      = (const float*)d_in[0];
  const float* EFR    = (const float*)d_in[1];
  const int*   EI     = (const int*)  d_in[2];
  const float* NS     = (const float*)d_in[3];
  const float* ES     = (const float*)d_in[4];
  const float* IN_W1  = (const float*)d_in[5];
  const float* IN_B1  = (const float*)d_in[6];
  const float* IN_W2  = (const float*)d_in[7];
  const float* IN_B2  = (const float*)d_in[8];
  const float* QKV_W  = (const float*)d_in[9];
  const float* QKV_B  = (const float*)d_in[10];
  const float* OUT_W  = (const float*)d_in[11];
  const float* OUT_B  = (const float*)d_in[12];
  const float* LN1S   = (const float*)d_in[13];
  const float* LN1B   = (const float*)d_in[14];
  const float* FFW1   = (const float*)d_in[15];
  const float* FFB1   = (const float*)d_in[16];
  const float* FFW2   = (const float*)d_in[17];
  const float* FFB2   = (const float*)d_in[18];
  const float* LN2S   = (const float*)d_in[19];
  const float* LN2B   = (const float*)d_in[20];
  const float* EIN_W1 = (const float*)d_in[21];
  const float* EIN_B1 = (const float*)d_in[22];
  const float* EIN_W2 = (const float*)d_in[23];
  const float* EIN_B2 = (const float*)d_in[24];
  const float* AD_W1  = (const float*)d_in[25];
  const float* AD_B1  = (const float*)d_in[26];
  const float* AD_W2  = (const float*)d_in[27];
  const float* AD_B2  = (const float*)d_in[28];
  const float* AR_W1  = (const float*)d_in[29];
  const float* AR_B1  = (const float*)d_in[30];
  const float* AR_W2  = (const float*)d_in[31];
  const float* AR_B2  = (const float*)d_in[32];
  const float* GC_W1  = (const float*)d_in[33];
  const float* GC_B1  = (const float*)d_in[34];
  const float* GC_W2  = (const float*)d_in[35];
  const float* GC_B2  = (const float*)d_in[36];
  const float* EN_W1  = (const float*)d_in[37];
  const float* EN_B1  = (const float*)d_in[38];
  const float* EN_W2  = (const float*)d_in[39];
  const float* EN_B2  = (const float*)d_in[40];

  char* ws = (char*)d_ws;
  u16*   pool  = (u16*)  (ws + WS_WT);
  u16*   efnn  = (u16*)  (ws + WS_EFNN);
  float* alpha = (float*)(ws + WS_ALPHA);
  float* h     = (float*)(ws + WS_H);
  float* qkvb  = (float*)(ws + WS_QKV);
  float* obuf  = (float*)(ws + WS_OBUF);
  float* tmpA  = (float*)(ws + WS_TMPA);
  float* tmpB  = (float*)(ws + WS_TMPB);
  float* x1    = (float*)(ws + WS_X1);
  float* num   = (float*)(ws + WS_NUM);
  float* den   = (float*)(ws + WS_DEN);
  float* xs    = (float*)(ws + WS_XS);

  // ---- weight conversion jobs ----
  CvtJobs jb;
  int idx = 0, cum = 0;
  auto addjob = [&](const float* s, int K, int Nc, int Kp){
    jb.src[idx] = s; jb.K[idx] = K; jb.Nc[idx] = Nc; jb.Kp[idx] = Kp;
    jb.cum[idx] = cum; cum += Nc * Kp; idx++;
  };
  addjob(IN_W1, 19, 96, 32);
  addjob(IN_W2, 96, 96, 96);
  for (int l = 0; l < 3; l++) addjob(QKV_W + (size_t)l*96*288, 96, 288, 96);
  for (int l = 0; l < 3; l++) addjob(OUT_W + (size_t)l*96*96,  96, 96,  96);
  for (int l = 0; l < 3; l++) addjob(FFW1  + (size_t)l*96*192, 96, 192, 96);
  for (int l = 0; l < 3; l++) addjob(FFW2  + (size_t)l*192*96, 192, 96, 192);
  addjob(EIN_W1, 12, 64, 32);
  addjob(EIN_W2, 64, 64, 64);
  addjob(AD_W1,  64, 64, 64);
  addjob(AR_W1,  64, 64, 64);
  for (int i = 0; i < 2; i++) addjob(GC_W1 + (size_t)i*192*192, 192, 192, 192);
  for (int i = 0; i < 2; i++) addjob(GC_W2 + (size_t)i*192*96,  192, 96,  192);
  addjob(EN_W1, 268, 96, 288);
  jb.cum[idx] = cum;   // == POOL_TOT

  k_cvt<<<(POOL_TOT + 255)/256, 256, 0, stream>>>(jb, pool);

  // ---- node embedding ----
  k_xscale<<<(NN*19 + 255)/256, 256, 0, stream>>>(X, NS, xs);
  k_gemm<6,1,1><<<32, 256, 0, stream>>>(xs, 19, pool + IN1T, IN_B1, tmpA);
  k_gemm<6,3,1><<<32, 256, 0, stream>>>(tmpA, 96, pool + IN2T, IN_B2, h);

  // ---- edge MLPs + attention weights ----
  k_edge<<<EE/64, 256, 0, stream>>>(EFR, ES, pool, EIN_B1, EIN_B2,
                                    AD_B1, AD_W2, AD_B2, AR_B1, AR_W2, AR_B2, efnn, alpha);
  (void)hipMemsetAsync(den, 0, NN*4, stream);
  k_den<<<(2*EE)/256, 256, 0, stream>>>(EI, alpha, den);

  // ---- 3 encoder layers ----
  for (int l = 0; l < 3; l++){
    k_gemm<18,3,0><<<32, 256, 0, stream>>>(h, 96, pool + QKVT + l*27648, QKV_B + l*288, qkvb);
    k_attn<<<384, 256, 0, stream>>>(qkvb, obuf);
    k_gemm<6,3,0><<<32, 256, 0, stream>>>(obuf, 96, pool + OUTT + l*9216, OUT_B + l*96, tmpA);
    k_ln<<<512, 256, 0, stream>>>(h, tmpA, LN1S + l*96, LN1B + l*96, x1);
    k_gemm<12,3,2><<<32, 256, 0, stream>>>(x1, 96, pool + FF1T + l*18432, FFB1 + l*192, tmpB);
    k_gemm<6,6,0><<<32, 256, 0, stream>>>(tmpB, 192, pool + FF2T + l*18432, FFB2 + l*96, tmpA);
    k_ln<<<512, 256, 0, stream>>>(x1, tmpA, LN2S + l*96, LN2B + l*96, h);
  }

  // ---- 2 graph-conv iterations ----
  for (int it = 0; it < 2; it++){
    (void)hipMemsetAsync(num, 0, NN*96*4, stream);
    k_gc<<<(2*EE)/128, 256, 0, stream>>>(h, EI, alpha,
        pool + GC1T + it*36864, pool + GC2T + it*18432,
        GC_B1 + it*192, GC_B2 + it*96, num);
    k_gcnode0<<<1, 256, 0, stream>>>(h, GC_W1 + (size_t)it*192*192, GC_B1 + it*192,
                                     GC_W2 + (size_t)it*192*96, GC_B2 + it*96, num);
    k_hupd<<<(NN*96)/256, 256, 0, stream>>>(num, den, h);
  }

  // ---- final predictor ----
  k_final<<<EE/64, 256, 0, stream>>>(h, EI, efnn, EFR, ES,
                                     pool + EN1T, EN_B1, EN_W2, EN_B2, (float*)d_out);
}

// Round 2
// 1724.906 us; speedup vs baseline: 1.4876x; 1.4876x over previous
//
#include <hip/hip_runtime.h>

// ---------------- constants ----------------
#define NN 2048
#define EE 262144

typedef __attribute__((ext_vector_type(8))) short bf16x8;
typedef __attribute__((ext_vector_type(4))) float f32x4;
typedef unsigned int u32;
typedef unsigned short u16;

__device__ __forceinline__ u16 f2bf(float f){
  u32 u = __builtin_bit_cast(u32, f);
  u32 r = u + 0x7FFFu + ((u >> 16) & 1u);
  return (u16)(r >> 16);
}
__device__ __forceinline__ float bf2f(u16 h){
  u32 u = ((u32)h) << 16;
  return __builtin_bit_cast(float, u);
}
__device__ __forceinline__ int swzb(int byte, int row){ return byte ^ ((row & 7) << 4); }
__device__ __forceinline__ float lrelu(float v){ return v > 0.f ? v : 0.01f * v; }

// ---------------- ws layout (bytes) ----------------
static const size_t WS_WT    = 0;                    // u16 pool (772096 B)
static const size_t WS_EFNN  = 772096;               // u16 E*64
static const size_t WS_ALPHA = WS_EFNN  + 33554432;  // f32 2E  (a_dir | a_rev)
static const size_t WS_H     = WS_ALPHA + 2097152;   // f32 N*96
static const size_t WS_QKV   = WS_H     + 786432;    // f32 N*288
static const size_t WS_OBUF  = WS_QKV   + 2359296;   // f32 N*96
static const size_t WS_TMPA  = WS_OBUF  + 786432;    // f32 N*96
static const size_t WS_TMPB  = WS_TMPA  + 786432;    // f32 N*192
static const size_t WS_X1    = WS_TMPB  + 1572864;   // f32 N*96
static const size_t WS_NUM   = WS_X1    + 786432;    // f32 N*96
static const size_t WS_DEN   = WS_NUM   + 786432;    // f32 N (pad)
static const size_t WS_XS    = WS_DEN   + 8192;      // f32 N*19 (pad)
static const size_t WS_HBF   = WS_XS    + 155648;    // u16 N*96
static const size_t WS_SIDX  = WS_HBF   + 393216;    // int2 2E
static const size_t WS_ALPS  = WS_SIDX  + 4194304;   // f32 2E (sorted alpha)
static const size_t WS_CNT   = WS_ALPS  + 2097152;   // int N
static const size_t WS_OFFS  = WS_CNT   + 8192;      // int N+1 (pad)

// pool element offsets (bf16, weights transposed [Nc][Kpad])
#define IN1T 0
#define IN2T 3072
#define QKVT 12288
#define OUTT 95232
#define FF1T 122880
#define FF2T 178176
#define EIN1T 233472
#define EIN2T 235520
#define AD1T 239616
#define AR1T 243712
#define GC1T 247808
#define GC2T 321536
#define EN1T 358400
#define POOL_TOT 386048

// ---------------- weight convert (f32 -> bf16, transposed, K-padded) ----------------
struct CvtJobs {
  const float* src[23];
  int K[23], Nc[23], Kp[23];
  int cum[24];
};

__global__ __launch_bounds__(256) void k_cvt(CvtJobs jb, u16* __restrict__ pool){
  int i = blockIdx.x * 256 + threadIdx.x;
  if (i >= jb.cum[23]) return;
  int j = 0;
  while (i >= jb.cum[j + 1]) j++;
  int loc = i - jb.cum[j];
  int Kp = jb.Kp[j];
  int n = loc / Kp, k = loc - n * Kp;
  float v = (k < jb.K[j]) ? jb.src[j][(size_t)k * jb.Nc[j] + n] : 0.f;
  pool[i] = f2bf(v);
}

__global__ __launch_bounds__(256) void k_xscale(const float* __restrict__ X, const float* __restrict__ ns,
                                                float* __restrict__ xs){
  int i = blockIdx.x * 256 + threadIdx.x;
  if (i < NN * 19) xs[i] = X[i] / ns[i % 19];
}

__global__ __launch_bounds__(256) void k_h2bf(const float* __restrict__ h, u16* __restrict__ hbf){
  int i = blockIdx.x * 256 + threadIdx.x;
  if (i < NN * 96) hbf[i] = f2bf(h[i]);
}

// ---------------- destination sort (counting sort over 2E edge rows) ----------------
__global__ __launch_bounds__(256) void k_hist(const int* __restrict__ ei, int* __restrict__ cnt){
  int g = blockIdx.x * 256 + threadIdx.x;
  int i1 = (g < EE) ? ei[2*g] : ei[2*(g - EE) + 1];
  atomicAdd(cnt + i1, 1);
}

__global__ __launch_bounds__(256) void k_scan(const int* __restrict__ cnt, int* __restrict__ offs){
  __shared__ int wsum[4], wbase[4];
  int t = threadIdx.x;
  int base = t * 8;
  int c[8]; int T = 0;
  #pragma unroll
  for (int i = 0; i < 8; i++){ c[i] = cnt[base + i]; T += c[i]; }
  int lane = t & 63, wv = t >> 6;
  int inc = T;
  #pragma unroll
  for (int st = 1; st < 64; st <<= 1){
    int v = __shfl_up(inc, st);
    if (lane >= st) inc += v;
  }
  if (lane == 63) wsum[wv] = inc;
  __syncthreads();
  if (t == 0){ int r = 0; for (int w2 = 0; w2 < 4; w2++){ wbase[w2] = r; r += wsum[w2]; } }
  __syncthreads();
  int run = wbase[wv] + inc - T;
  #pragma unroll
  for (int i = 0; i < 8; i++){ offs[base + i] = run; run += c[i]; }
  if (t == 255) offs[2048] = run;
}

__global__ __launch_bounds__(256) void k_scatter(const int* __restrict__ ei, const float* __restrict__ alpha,
    const int* __restrict__ offs, int* __restrict__ rk, int2* __restrict__ sidx, float* __restrict__ alphaS){
  int g = blockIdx.x * 256 + threadIdx.x;
  int i1, i2;
  if (g < EE){ i1 = ei[2*g]; i2 = ei[2*g + 1]; }
  else { int gg = g - EE; i1 = ei[2*gg + 1]; i2 = ei[2*gg]; }
  int r = atomicAdd(rk + i1, 1);
  int pos = offs[i1] + r;
  sidx[pos] = make_int2(i1, i2);
  alphaS[pos] = alpha[g];
}

__global__ __launch_bounds__(256) void k_dens(const int* __restrict__ offs, const float* __restrict__ alphaS,
                                              float* __restrict__ den){
  int n = blockIdx.x * 4 + (threadIdx.x >> 6);
  int lane = threadIdx.x & 63;
  int b = offs[n], e = offs[n + 1];
  float s = 0.f;
  for (int i = b + lane; i < e; i += 64) s += alphaS[i];
  #pragma unroll
  for (int st = 1; st < 64; st <<= 1) s += __shfl_xor(s, st);
  if (lane == 0) den[n] = s + (n == 0 ? 2048.f : 0.f);
}

// ---------------- MFMA tile helpers ----------------
// A in LDS [rows][SR bytes], swizzled. frag: A lane l -> row l&15, k (l>>4)*8+j ; D: row=(l>>4)*4+q, col=l&15
template<int NT, int KS, int SR>
__device__ __forceinline__ void tile_gemm(const char* sm, int aBase, int bBase, int lane, f32x4* acc){
  const int r15 = lane & 15;
  const int kb = (lane >> 4) * 16;
  #pragma unroll
  for (int ks = 0; ks < KS; ks++){
    bf16x8 a = *(const bf16x8*)(sm + aBase + swzb(r15*SR + ks*64 + kb, r15));
    #pragma unroll
    for (int ct = 0; ct < NT; ct++){
      int n = ct*16 + r15;
      bf16x8 b = *(const bf16x8*)(sm + bBase + swzb(n*SR + ks*64 + kb, n));
      acc[ct] = __builtin_amdgcn_mfma_f32_16x16x32_bf16(a, b, acc[ct], 0, 0, 0);
    }
  }
}

// B directly from global (L2-hot weight pool), un-swizzled [Nc][Kp] bf16
template<int NT, int KS, int SR>
__device__ __forceinline__ void tile_gemm_gb(const char* sm, int aBase, const u16* __restrict__ W, int Kp,
                                             int lane, f32x4* acc){
  const int r15 = lane & 15;
  const int kb = (lane >> 4) * 16;
  const int ke = (lane >> 4) * 8;
  #pragma unroll
  for (int ks = 0; ks < KS; ks++){
    bf16x8 a = *(const bf16x8*)(sm + aBase + swzb(r15*SR + ks*64 + kb, r15));
    #pragma unroll
    for (int ct = 0; ct < NT; ct++){
      int n = ct*16 + r15;
      bf16x8 b = *(const bf16x8*)(W + n*Kp + ks*32 + ke);
      acc[ct] = __builtin_amdgcn_mfma_f32_16x16x32_bf16(a, b, acc[ct], 0, 0, 0);
    }
  }
}

// ---------------- generic GEMM: C[M][Nc] = act(A[M][K] @ W + bias), M mult of 64 ----------------
template<int NT, int KS, int ACT>
__global__ __launch_bounds__(256) void k_gemm(const float* __restrict__ A, int K,
    const u16* __restrict__ Wt, const float* __restrict__ bias, float* __restrict__ C)
{
  constexpr int Kpad = KS * 32;
  constexpr int Nc = NT * 16;
  constexpr int SR = (Kpad*2 + 127) / 128 * 128;
  constexpr int ABASE = Nc * SR;
  __shared__ __align__(16) char smem[Nc*SR + 64*SR];
  constexpr int KP8 = Kpad / 8;
  for (int j = threadIdx.x; j < Nc*KP8; j += 256){
    int n = j / KP8;
    *(uint4*)(smem + swzb(n*SR + (j - n*KP8)*16, n)) = ((const uint4*)Wt)[j];
  }
  const int row0 = blockIdx.x * 64;
  for (int j = threadIdx.x; j < 64*(Kpad/2); j += 256){
    int r = j / (Kpad/2); int c = (j - r*(Kpad/2)) * 2;
    const float* ap = A + (size_t)(row0 + r)*K + c;
    float f0 = (c < K) ? ap[0] : 0.f;
    float f1 = (c + 1 < K) ? ap[1] : 0.f;
    *(u32*)(smem + ABASE + swzb(r*SR + c*2, r)) = (u32)f2bf(f0) | ((u32)f2bf(f1) << 16);
  }
  __syncthreads();
  const int lane = threadIdx.x & 63, w = threadIdx.x >> 6;
  const int r15 = lane & 15;
  f32x4 acc[NT] = {};
  tile_gemm<NT, KS, SR>(smem, ABASE + w*16*SR, 0, lane, acc);
  #pragma unroll
  for (int ct = 0; ct < NT; ct++){
    int col = ct*16 + r15;
    float bs = bias[col];
    #pragma unroll
    for (int q = 0; q < 4; q++){
      int r = row0 + w*16 + (lane >> 4)*4 + q;
      float v = acc[ct][q] + bs;
      if (ACT == 1) v = lrelu(v);
      if (ACT == 2) v = v > 0.f ? v : 0.f;
      C[(size_t)r*Nc + col] = v;
    }
  }
}

// ---------------- LayerNorm(a+b) ----------------
__global__ __launch_bounds__(256) void k_ln(const float* __restrict__ A, const float* __restrict__ B,
    const float* __restrict__ sc, const float* __restrict__ bi, float* __restrict__ out)
{
  const int row = blockIdx.x*4 + (threadIdx.x >> 6);
  const int lane = threadIdx.x & 63;
  const float* ap = A + row*96; const float* bp = B + row*96;
  float v1 = ap[lane] + bp[lane];
  float v2 = (lane < 32) ? (ap[64+lane] + bp[64+lane]) : 0.f;
  float sum = v1 + v2, sq = v1*v1 + v2*v2;
  #pragma unroll
  for (int st = 1; st < 64; st <<= 1){ sum += __shfl_xor(sum, st); sq += __shfl_xor(sq, st); }
  float mean = sum * (1.f/96.f);
  float var = sq * (1.f/96.f) - mean*mean;
  float rs = rsqrtf(var + 1e-5f);
  out[row*96 + lane] = (v1 - mean)*rs*sc[lane] + bi[lane];
  if (lane < 32) out[row*96 + 64 + lane] = (v2 - mean)*rs*sc[64+lane] + bi[64+lane];
}

// ---------------- fused flash-style attention (fp32), one (head, 64-row) block ----------------
__global__ __launch_bounds__(256) void k_attn(const float* __restrict__ qkv, float* __restrict__ obuf){
  __shared__ float KV[2][2048*9];
  const int tid = threadIdx.x;
  const int head = blockIdx.x >> 5, rb = blockIdx.x & 31;
  for (int fl = tid; fl < 32768; fl += 256){
    int m = fl >> 4, idx = fl & 15, isV = idx >> 3, d = idx & 7;
    KV[isV][m*9 + d] = qkv[m*288 + 96 + isV*96 + head*8 + d];
  }
  __syncthreads();
  const int lane = tid & 63, w = tid >> 6;
  for (int rr = 0; rr < 16; rr++){
    int row = rb*64 + w*16 + rr;
    const float* qp = qkv + (size_t)row*288 + head*8;
    float q0=qp[0],q1=qp[1],q2=qp[2],q3=qp[3],q4=qp[4],q5=qp[5],q6=qp[6],q7=qp[7];
    float mx = -1e30f, sm = 0.f;
    float o[8] = {0,0,0,0,0,0,0,0};
    for (int j = 0; j < 32; j++){
      int m = lane + 64*j;
      const float* kp = &KV[0][m*9];
      float s = q0*kp[0]+q1*kp[1]+q2*kp[2]+q3*kp[3]+q4*kp[4]+q5*kp[5]+q6*kp[6]+q7*kp[7];
      s *= 0.35355339059327373f;
      const float* vp = &KV[1][m*9];
      if (s <= mx){
        float p = __expf(s - mx);
        sm += p;
        #pragma unroll
        for (int d = 0; d < 8; d++) o[d] += p * vp[d];
      } else {
        float scl = __expf(mx - s);
        sm = sm*scl + 1.f;
        #pragma unroll
        for (int d = 0; d < 8; d++) o[d] = o[d]*scl + vp[d];
        mx = s;
      }
    }
    #pragma unroll
    for (int st = 1; st < 64; st <<= 1){
      float omx = __shfl_xor(mx, st);
      float osm = __shfl_xor(sm, st);
      float nm = fmaxf(mx, omx);
      float ea = __expf(mx - nm), eb = __expf(omx - nm);
      #pragma unroll
      for (int d = 0; d < 8; d++){
        float od = __shfl_xor(o[d], st);
        o[d] = o[d]*ea + od*eb;
      }
      sm = sm*ea + osm*eb;
      mx = nm;
    }
    if (lane == 0){
      float inv = 1.f / sm;
      float* op = obuf + (size_t)row*96 + head*8;
      #pragma unroll
      for (int d = 0; d < 8; d++) op[d] = o[d]*inv;
    }
  }
}

// ---------------- fused edge MLPs: ef -> ein1 -> ein2 (efnn) -> {ad, ar} -> alpha ----------------
__global__ __launch_bounds__(256) void k_edge(const float* __restrict__ efr, const float* __restrict__ es,
    const u16* __restrict__ pool,
    const float* __restrict__ eb1, const float* __restrict__ eb2,
    const float* __restrict__ adb1, const float* __restrict__ adw2, const float* __restrict__ adb2,
    const float* __restrict__ arb1, const float* __restrict__ arw2, const float* __restrict__ arb2,
    u16* __restrict__ efnn, float* __restrict__ alpha)
{
  __shared__ __align__(16) char smem[49152];
  const int tid = threadIdx.x;
  const int e0 = blockIdx.x * 64;
  for (int j = tid; j < 256; j += 256){
    int n = j >> 2;
    *(uint4*)(smem + swzb(n*128 + (j&3)*16, n)) = ((const uint4*)(pool + EIN1T))[j];
  }
  for (int j = tid; j < 512; j += 256){
    int n = j >> 3; int b = n*128 + (j&7)*16;
    *(uint4*)(smem + 8192  + swzb(b, n)) = ((const uint4*)(pool + EIN2T))[j];
    *(uint4*)(smem + 16384 + swzb(b, n)) = ((const uint4*)(pool + AD1T))[j];
    *(uint4*)(smem + 24576 + swzb(b, n)) = ((const uint4*)(pool + AR1T))[j];
  }
  for (int j = tid; j < 64*16; j += 256){
    int r = j >> 4; int c = (j & 15) * 2;
    float f0 = 0.f, f1 = 0.f;
    if (c < 12)     f0 = (efr[(e0+r)*12 + c]     + 1e-4f) / es[c];
    if (c + 1 < 12) f1 = (efr[(e0+r)*12 + c + 1] + 1e-4f) / es[c+1];
    *(u32*)(smem + 32768 + swzb(r*128 + c*2, r)) = (u32)f2bf(f0) | ((u32)f2bf(f1) << 16);
  }
  __syncthreads();
  const int lane = tid & 63, w = tid >> 6;
  const int r15 = lane & 15;

  auto store_lds = [&](f32x4* acc, int base, const float* bias){
    #pragma unroll
    for (int ct = 0; ct < 4; ct++){
      int col = ct*16 + r15;
      float bs = bias[col];
      #pragma unroll
      for (int q = 0; q < 4; q++){
        int row = w*16 + (lane >> 4)*4 + q;
        *(u16*)(smem + base + swzb(row*128 + col*2, row)) = f2bf(lrelu(acc[ct][q] + bs));
      }
    }
  };

  { f32x4 acc[4] = {};
    tile_gemm<4,1,128>(smem, 32768 + w*2048, 0, lane, acc);
    store_lds(acc, 40960, eb1); }
  { f32x4 acc[4] = {};
    tile_gemm<4,2,128>(smem, 40960 + w*2048, 8192, lane, acc);
    store_lds(acc, 32768, eb2); }
  __syncthreads();
  for (int j = tid; j < 2048; j += 256){
    int r = j >> 5;
    ((u32*)efnn)[e0*32 + j] = *(const u32*)(smem + 32768 + swzb(r*128 + (j&31)*4, r));
  }
  { f32x4 acc[4] = {};
    tile_gemm<4,2,128>(smem, 32768 + w*2048, 16384, lane, acc);
    store_lds(acc, 40960, adb1); }
  __syncthreads();
  { int row = tid >> 2, part = tid & 3;
    float s = 0.f;
    #pragma unroll
    for (int i = 0; i < 16; i++){
      int k = part*16 + i;
      s += bf2f(*(const u16*)(smem + 40960 + swzb(row*128 + k*2, row))) * adw2[k];
    }
    s += __shfl_xor(s, 1); s += __shfl_xor(s, 2);
    if (part == 0) alpha[e0 + row] = 1.f / (1.f + __expf(-(s + adb2[0]))); }
  __syncthreads();
  { f32x4 acc[4] = {};
    tile_gemm<4,2,128>(smem, 32768 + w*2048, 24576, lane, acc);
    store_lds(acc, 40960, arb1); }
  __syncthreads();
  { int row = tid >> 2, part = tid & 3;
    float s = 0.f;
    #pragma unroll
    for (int i = 0; i < 16; i++){
      int k = part*16 + i;
      s += bf2f(*(const u16*)(smem + 40960 + swzb(row*128 + k*2, row))) * arw2[k];
    }
    s += __shfl_xor(s, 1); s += __shfl_xor(s, 2);
    if (part == 0) alpha[EE + e0 + row] = 1.f / (1.f + __expf(-(s + arb2[0]))); }
}

// ---------------- graph-conv over destination-sorted rows (gather -> MLP -> segment scan) ----------------
__global__ __launch_bounds__(256) void k_gc2(const u16* __restrict__ hbf, const int2* __restrict__ sidx,
    const float* __restrict__ alphaS, const u16* __restrict__ wt1, const u16* __restrict__ wt2,
    const float* __restrict__ b1, const float* __restrict__ b2, float* __restrict__ num)
{
  // LDS: [0,50176) act region (bf16 [128][384B] swz for in/h1, f32 [128][392B] for out)
  //      [50176) nid[128] int ; [50688) i2s[128] int ; [51200) alph[128] f32
  __shared__ __align__(16) char smem[51712];
  int*   nid  = (int*)(smem + 50176);
  int*   i2s  = (int*)(smem + 50688);
  float* alph = (float*)(smem + 51200);
  const int tid = threadIdx.x;
  const int row0 = blockIdx.x * 128;
  if (tid < 128){
    int2 p = sidx[row0 + tid];
    nid[tid] = p.x; i2s[tid] = p.y;
    alph[tid] = alphaS[row0 + tid];
  }
  __syncthreads();
  // gather [128][192] bf16 input from hbf in 16B chunks
  for (int j = tid; j < 128*24; j += 256){
    int r = j / 24, q = j - (j / 24)*24;
    int c8 = q * 8;
    int sr = (q < 12) ? nid[r] : i2s[r];
    int cc = (q < 12) ? c8 : c8 - 96;
    bf16x8 v = *(const bf16x8*)(hbf + sr*96 + cc);
    *(bf16x8*)(smem + swzb(r*384 + c8*2, r)) = v;
  }
  __syncthreads();
  const int lane = tid & 63, w = tid >> 6;
  const int wr = w >> 1, wc = w & 1;          // 2x2 wave grid: 64 rows x 96 cols each
  const int r15 = lane & 15;
  const int kb = (lane >> 4) * 16;            // byte offset within LDS row
  const int ke = (lane >> 4) * 8;             // element offset within global W row
  f32x4 acc[4][6] = {};
  #pragma unroll
  for (int ks = 0; ks < 6; ks++){
    bf16x8 a[4];
    #pragma unroll
    for (int rt = 0; rt < 4; rt++){
      int row = wr*64 + rt*16 + r15;
      a[rt] = *(const bf16x8*)(smem + swzb(row*384 + ks*64 + kb, row));
    }
    #pragma unroll
    for (int ct = 0; ct < 6; ct++){
      int n = wc*96 + ct*16 + r15;
      bf16x8 b = *(const bf16x8*)(wt1 + n*192 + ks*32 + ke);
      #pragma unroll
      for (int rt = 0; rt < 4; rt++)
        acc[rt][ct] = __builtin_amdgcn_mfma_f32_16x16x32_bf16(a[rt], b, acc[rt][ct], 0, 0, 0);
    }
  }
  __syncthreads();
  #pragma unroll
  for (int ct = 0; ct < 6; ct++){
    int col = wc*96 + ct*16 + r15;
    float bs = b1[col];
    #pragma unroll
    for (int rt = 0; rt < 4; rt++){
      #pragma unroll
      for (int q = 0; q < 4; q++){
        int row = wr*64 + rt*16 + (lane >> 4)*4 + q;
        *(u16*)(smem + swzb(row*384 + col*2, row)) = f2bf(lrelu(acc[rt][ct][q] + bs));
      }
    }
  }
  __syncthreads();
  f32x4 acc2[4][3] = {};
  #pragma unroll
  for (int ks = 0; ks < 6; ks++){
    bf16x8 a[4];
    #pragma unroll
    for (int rt = 0; rt < 4; rt++){
      int row = wr*64 + rt*16 + r15;
      a[rt] = *(const bf16x8*)(smem + swzb(row*384 + ks*64 + kb, row));
    }
    #pragma unroll
    for (int ct = 0; ct < 3; ct++){
      int n = wc*48 + ct*16 + r15;
      bf16x8 b = *(const bf16x8*)(wt2 + n*192 + ks*32 + ke);
      #pragma unroll
      for (int rt = 0; rt < 4; rt++)
        acc2[rt][ct] = __builtin_amdgcn_mfma_f32_16x16x32_bf16(a[rt], b, acc2[rt][ct], 0, 0, 0);
    }
  }
  __syncthreads();
  // write alpha-scaled f32 outputs, stride 392B (bank-spread)
  #pragma unroll
  for (int ct = 0; ct < 3; ct++){
    int col = wc*48 + ct*16 + r15;
    float bs = b2[col];
    #pragma unroll
    for (int rt = 0; rt < 4; rt++){
      #pragma unroll
      for (int q = 0; q < 4; q++){
        int row = wr*64 + rt*16 + (lane >> 4)*4 + q;
        *(float*)(smem + row*392 + col*4) = alph[row] * lrelu(acc2[rt][ct][q] + bs);
      }
    }
  }
  __syncthreads();
  // per-column segment scan over the (destination-sorted) 128 rows; ~2 atomics/(col,half)
  if (tid < 192){
    int hf = tid / 96;
    int c = tid - hf*96;
    int rbeg = hf*64, rend = rbeg + 64;
    float accv = 0.f;
    int cur = nid[rbeg];
    for (int r = rbeg; r < rend; r++){
      int n2 = nid[r];
      if (n2 != cur){ atomicAdd(num + cur*96 + c, accv); accv = 0.f; cur = n2; }
      accv += *(const float*)(smem + r*392 + c*4);
    }
    atomicAdd(num + cur*96 + c, accv);
  }
}

// the N rows with ind1=ind2=0 are identical: compute once, add 2048x
__global__ __launch_bounds__(256) void k_gcnode0(const float* __restrict__ h,
    const float* __restrict__ W1, const float* __restrict__ b1,
    const float* __restrict__ W2, const float* __restrict__ b2, float* __restrict__ num)
{
  __shared__ float in_s[192], h1_s[192];
  int t = threadIdx.x;
  if (t < 192) in_s[t] = h[t % 96];
  __syncthreads();
  if (t < 192){
    float s = b1[t];
    for (int k = 0; k < 192; k++) s += in_s[k] * W1[k*192 + t];
    h1_s[t] = lrelu(s);
  }
  __syncthreads();
  if (t < 96){
    float s = b2[t];
    for (int k = 0; k < 192; k++) s += h1_s[k] * W2[k*96 + t];
    num[t] += 2048.f * lrelu(s);
  }
}

__global__ __launch_bounds__(256) void k_hupd(const float* __restrict__ num, const float* __restrict__ den,
                                              float* __restrict__ h){
  int i = blockIdx.x * 256 + threadIdx.x;
  h[i] = num[i] / (den[i / 96] + 1e-8f);
}

// ---------------- final per-edge predictor ----------------
__global__ __launch_bounds__(256) void k_final(const u16* __restrict__ hbf, const int* __restrict__ ei,
    const u16* __restrict__ efnn, const float* __restrict__ efr, const float* __restrict__ es,
    const u16* __restrict__ en1, const float* __restrict__ enb1,
    const float* __restrict__ enw2, const float* __restrict__ enb2, float* __restrict__ out)
{
  // LDS: [0,40960) bufA [64][640B] swz ; [40960,65792) bufB f32 [64][97]
  __shared__ __align__(16) char smem[65792];
  const int tid = threadIdx.x;
  const int e0 = blockIdx.x * 64;
  for (int j = tid; j < 64*36; j += 256){
    int r = j / 36, q = j - (j / 36)*36;
    int e = e0 + r;
    if (q < 32){
      bf16x8 v;
      if (q < 24){
        int idx = (q < 12) ? ei[2*e] : ei[2*e + 1];
        int cc = (q < 12) ? q*8 : q*8 - 96;
        v = *(const bf16x8*)(hbf + idx*96 + cc);
      } else {
        v = *(const bf16x8*)(efnn + e*64 + (q - 24)*8);
      }
      *(bf16x8*)(smem + swzb(r*640 + q*16, r)) = v;
    } else {
      u16 pk[8];
      int c0 = 256 + (q - 32)*8;
      #pragma unroll
      for (int i = 0; i < 8; i++){
        int cc = c0 + i - 256;
        pk[i] = (cc < 12) ? f2bf((efr[e*12 + cc] + 1e-4f) / es[cc]) : (u16)0;
      }
      *(bf16x8*)(smem + swzb(r*640 + c0*2, r)) = *(bf16x8*)pk;
    }
  }
  __syncthreads();
  const int lane = tid & 63, w = tid >> 6;
  const int r15 = lane & 15;
  f32x4 acc[6] = {};
  tile_gemm_gb<6,9,640>(smem, w*10240, en1, 288, lane, acc);
  #pragma unroll
  for (int ct = 0; ct < 6; ct++){
    int col = ct*16 + r15;
    float bs = enb1[col];
    #pragma unroll
    for (int q = 0; q < 4; q++){
      int row = w*16 + (lane >> 4)*4 + q;
      *(float*)(smem + 40960 + (row*97 + col)*4) = lrelu(acc[ct][q] + bs);
    }
  }
  __syncthreads();
  int row = tid >> 2, part = tid & 3;
  float s = 0.f;
  #pragma unroll
  for (int i = 0; i < 24; i++){
    int k = part*24 + i;
    s += *(const float*)(smem + 40960 + (row*97 + k)*4) * enw2[k];
  }
  s += __shfl_xor(s, 1); s += __shfl_xor(s, 2);
  if (part == 0) out[e0 + row] = 1.f / (1.f + __expf(-(s + enb2[0])));
}

// ---------------- host ----------------
extern "C" void kernel_launch(void* const* d_in, const int* in_sizes, int n_in,
                              void* d_out, int out_size, void* d_ws, size_t ws_size,
                              hipStream_t stream) {
  (void)in_sizes; (void)n_in; (void)out_size; (void)ws_size;
  const float* X      = (const float*)d_in[0];
  const float* EFR    = (const float*)d_in[1];
  const int*   EI     = (const int*)  d_in[2];
  const float* NS     = (const float*)d_in[3];
  const float* ES     = (const float*)d_in[4];
  const float* IN_W1  = (const float*)d_in[5];
  const float* IN_B1  = (const float*)d_in[6];
  const float* IN_W2  = (const float*)d_in[7];
  const float* IN_B2  = (const float*)d_in[8];
  const float* QKV_W  = (const float*)d_in[9];
  const float* QKV_B  = (const float*)d_in[10];
  const float* OUT_W  = (const float*)d_in[11];
  const float* OUT_B  = (const float*)d_in[12];
  const float* LN1S   = (const float*)d_in[13];
  const float* LN1B   = (const float*)d_in[14];
  const float* FFW1   = (const float*)d_in[15];
  const float* FFB1   = (const float*)d_in[16];
  const float* FFW2   = (const float*)d_in[17];
  const float* FFB2   = (const float*)d_in[18];
  const float* LN2S   = (const float*)d_in[19];
  const float* LN2B   = (const float*)d_in[20];
  const float* EIN_W1 = (const float*)d_in[21];
  const float* EIN_B1 = (const float*)d_in[22];
  const float* EIN_W2 = (const float*)d_in[23];
  const float* EIN_B2 = (const float*)d_in[24];
  const float* AD_W1  = (const float*)d_in[25];
  const float* AD_B1  = (const float*)d_in[26];
  const float* AD_W2  = (const float*)d_in[27];
  const float* AD_B2  = (const float*)d_in[28];
  const float* AR_W1  = (const float*)d_in[29];
  const float* AR_B1  = (const float*)d_in[30];
  const float* AR_W2  = (const float*)d_in[31];
  const float* AR_B2  = (const float*)d_in[32];
  const float* GC_W1  = (const float*)d_in[33];
  const float* GC_B1  = (const float*)d_in[34];
  const float* GC_W2  = (const float*)d_in[35];
  const float* GC_B2  = (const float*)d_in[36];
  const float* EN_W1  = (const float*)d_in[37];
  const float* EN_B1  = (const float*)d_in[38];
  const float* EN_W2  = (const float*)d_in[39];
  const float* EN_B2  = (const float*)d_in[40];

  char* ws = (char*)d_ws;
  u16*   pool   = (u16*)  (ws + WS_WT);
  u16*   efnn   = (u16*)  (ws + WS_EFNN);
  float* alpha  = (float*)(ws + WS_ALPHA);
  float* h      = (float*)(ws + WS_H);
  float* qkvb   = (float*)(ws + WS_QKV);
  float* obuf   = (float*)(ws + WS_OBUF);
  float* tmpA   = (float*)(ws + WS_TMPA);
  float* tmpB   = (float*)(ws + WS_TMPB);
  float* x1     = (float*)(ws + WS_X1);
  float* num    = (float*)(ws + WS_NUM);
  float* den    = (float*)(ws + WS_DEN);
  float* xs     = (float*)(ws + WS_XS);
  u16*   hbf    = (u16*)  (ws + WS_HBF);
  int2*  sidx   = (int2*) (ws + WS_SIDX);
  float* alphaS = (float*)(ws + WS_ALPS);
  int*   cnt    = (int*)  (ws + WS_CNT);
  int*   offs   = (int*)  (ws + WS_OFFS);

  // ---- weight conversion jobs ----
  CvtJobs jb;
  int idx = 0, cum = 0;
  auto addjob = [&](const float* s, int K, int Nc, int Kp){
    jb.src[idx] = s; jb.K[idx] = K; jb.Nc[idx] = Nc; jb.Kp[idx] = Kp;
    jb.cum[idx] = cum; cum += Nc * Kp; idx++;
  };
  addjob(IN_W1, 19, 96, 32);
  addjob(IN_W2, 96, 96, 96);
  for (int l = 0; l < 3; l++) addjob(QKV_W + (size_t)l*96*288, 96, 288, 96);
  for (int l = 0; l < 3; l++) addjob(OUT_W + (size_t)l*96*96,  96, 96,  96);
  for (int l = 0; l < 3; l++) addjob(FFW1  + (size_t)l*96*192, 96, 192, 96);
  for (int l = 0; l < 3; l++) addjob(FFW2  + (size_t)l*192*96, 192, 96, 192);
  addjob(EIN_W1, 12, 64, 32);
  addjob(EIN_W2, 64, 64, 64);
  addjob(AD_W1,  64, 64, 64);
  addjob(AR_W1,  64, 64, 64);
  for (int i = 0; i < 2; i++) addjob(GC_W1 + (size_t)i*192*192, 192, 192, 192);
  for (int i = 0; i < 2; i++) addjob(GC_W2 + (size_t)i*192*96,  192, 96,  192);
  addjob(EN_W1, 268, 96, 288);
  jb.cum[idx] = cum;

  k_cvt<<<(POOL_TOT + 255)/256, 256, 0, stream>>>(jb, pool);

  // ---- node embedding ----
  k_xscale<<<(NN*19 + 255)/256, 256, 0, stream>>>(X, NS, xs);
  k_gemm<6,1,1><<<32, 256, 0, stream>>>(xs, 19, pool + IN1T, IN_B1, tmpA);
  k_gemm<6,3,1><<<32, 256, 0, stream>>>(tmpA, 96, pool + IN2T, IN_B2, h);

  // ---- edge MLPs + attention weights ----
  k_edge<<<EE/64, 256, 0, stream>>>(EFR, ES, pool, EIN_B1, EIN_B2,
                                    AD_B1, AD_W2, AD_B2, AR_B1, AR_W2, AR_B2, efnn, alpha);

  // ---- destination sort + den ----
  (void)hipMemsetAsync(cnt, 0, NN*4, stream);
  k_hist<<<(2*EE)/256, 256, 0, stream>>>(EI, cnt);
  k_scan<<<1, 256, 0, stream>>>(cnt, offs);
  (void)hipMemsetAsync(cnt, 0, NN*4, stream);
  k_scatter<<<(2*EE)/256, 256, 0, stream>>>(EI, alpha, offs, cnt, sidx, alphaS);
  k_dens<<<NN/4, 256, 0, stream>>>(offs, alphaS, den);

  // ---- 3 encoder layers ----
  for (int l = 0; l < 3; l++){
    k_gemm<18,3,0><<<32, 256, 0, stream>>>(h, 96, pool + QKVT + l*27648, QKV_B + l*288, qkvb);
    k_attn<<<384, 256, 0, stream>>>(qkvb, obuf);
    k_gemm<6,3,0><<<32, 256, 0, stream>>>(obuf, 96, pool + OUTT + l*9216, OUT_B + l*96, tmpA);
    k_ln<<<512, 256, 0, stream>>>(h, tmpA, LN1S + l*96, LN1B + l*96, x1);
    k_gemm<12,3,2><<<32, 256, 0, stream>>>(x1, 96, pool + FF1T + l*18432, FFB1 + l*192, tmpB);
    k_gemm<6,6,0><<<32, 256, 0, stream>>>(tmpB, 192, pool + FF2T + l*18432, FFB2 + l*96, tmpA);
    k_ln<<<512, 256, 0, stream>>>(x1, tmpA, LN2S + l*96, LN2B + l*96, h);
  }

  // ---- 2 graph-conv iterations ----
  for (int it = 0; it < 2; it++){
    k_h2bf<<<(NN*96)/256, 256, 0, stream>>>(h, hbf);
    (void)hipMemsetAsync(num, 0, NN*96*4, stream);
    k_gc2<<<(2*EE)/128, 256, 0, stream>>>(hbf, sidx, alphaS,
        pool + GC1T + it*36864, pool + GC2T + it*18432,
        GC_B1 + it*192, GC_B2 + it*96, num);
    k_gcnode0<<<1, 256, 0, stream>>>(h, GC_W1 + (size_t)it*192*192, GC_B1 + it*192,
                                     GC_W2 + (size_t)it*192*96, GC_B2 + it*96, num);
    k_hupd<<<(NN*96)/256, 256, 0, stream>>>(num, den, h);
  }

  // ---- final predictor ----
  k_h2bf<<<(NN*96)/256, 256, 0, stream>>>(h, hbf);
  k_final<<<EE/64, 256, 0, stream>>>(hbf, EI, efnn, EFR, ES,
                                     pool + EN1T, EN_B1, EN_W2, EN_B2, (float*)d_out);
}

// Round 3
// 1316.203 us; speedup vs baseline: 1.9495x; 1.3105x over previous
//
#include <hip/hip_runtime.h>

// ---------------- constants ----------------
#define NN 2048
#define EE 262144

typedef __attribute__((ext_vector_type(8))) short bf16x8;
typedef __attribute__((ext_vector_type(4))) float f32x4;
typedef unsigned int u32;
typedef unsigned short u16;

__device__ __forceinline__ u16 f2bf(float f){
  u32 u = __builtin_bit_cast(u32, f);
  u32 r = u + 0x7FFFu + ((u >> 16) & 1u);
  return (u16)(r >> 16);
}
__device__ __forceinline__ float bf2f(u16 h){
  u32 u = ((u32)h) << 16;
  return __builtin_bit_cast(float, u);
}
__device__ __forceinline__ int swzb(int byte, int row){ return byte ^ ((row & 7) << 4); }
__device__ __forceinline__ float lrelu(float v){ return v > 0.f ? v : 0.01f * v; }

// ---------------- ws layout (bytes) ----------------
static const size_t WS_WT    = 0;                    // u16 pool (772096 B)
static const size_t WS_EFNN  = 772096;               // u16 E*64
static const size_t WS_ALPHA = WS_EFNN  + 33554432;  // f32 2E  (a_dir | a_rev)
static const size_t WS_H     = WS_ALPHA + 2097152;   // f32 N*96
static const size_t WS_QKV   = WS_H     + 786432;    // f32 N*288
static const size_t WS_OBUF  = WS_QKV   + 2359296;   // f32 N*96
static const size_t WS_TMPA  = WS_OBUF  + 786432;    // f32 N*96
static const size_t WS_TMPB  = WS_TMPA  + 786432;    // f32 N*192
static const size_t WS_X1    = WS_TMPB  + 1572864;   // f32 N*96
static const size_t WS_NUM   = WS_X1    + 786432;    // f32 N*96
static const size_t WS_DEN   = WS_NUM   + 786432;    // f32 N (pad)
static const size_t WS_XS    = WS_DEN   + 8192;      // f32 N*19 (pad)
static const size_t WS_HBF   = WS_XS    + 155648;    // u16 N*96
static const size_t WS_SIDX  = WS_HBF   + 393216;    // int2 2E
static const size_t WS_ALPS  = WS_SIDX  + 4194304;   // f32 2E (sorted alpha)
static const size_t WS_CNT   = WS_ALPS  + 2097152;   // int N
static const size_t WS_OFFS  = WS_CNT   + 8192;      // int N+1 (pad)

// pool element offsets (bf16, weights transposed [Nc][Kpad])
#define IN1T 0
#define IN2T 3072
#define QKVT 12288
#define OUTT 95232
#define FF1T 122880
#define FF2T 178176
#define EIN1T 233472
#define EIN2T 235520
#define AD1T 239616
#define AR1T 243712
#define GC1T 247808
#define GC2T 321536
#define EN1T 358400
#define POOL_TOT 386048

// ---------------- weight convert (f32 -> bf16, transposed, K-padded) ----------------
struct CvtJobs {
  const float* src[23];
  int K[23], Nc[23], Kp[23];
  int cum[24];
};

__global__ __launch_bounds__(256) void k_cvt(CvtJobs jb, u16* __restrict__ pool){
  int i = blockIdx.x * 256 + threadIdx.x;
  if (i >= jb.cum[23]) return;
  int j = 0;
  while (i >= jb.cum[j + 1]) j++;
  int loc = i - jb.cum[j];
  int Kp = jb.Kp[j];
  int n = loc / Kp, k = loc - n * Kp;
  float v = (k < jb.K[j]) ? jb.src[j][(size_t)k * jb.Nc[j] + n] : 0.f;
  pool[i] = f2bf(v);
}

__global__ __launch_bounds__(256) void k_xscale(const float* __restrict__ X, const float* __restrict__ ns,
                                                float* __restrict__ xs){
  int i = blockIdx.x * 256 + threadIdx.x;
  if (i < NN * 19) xs[i] = X[i] / ns[i % 19];
}

// ---------------- destination sort (counting sort over 2E edge rows) ----------------
__global__ __launch_bounds__(256) void k_hist(const int* __restrict__ ei, int* __restrict__ cnt){
  int g = blockIdx.x * 256 + threadIdx.x;
  int i1 = (g < EE) ? ei[2*g] : ei[2*(g - EE) + 1];
  atomicAdd(cnt + i1, 1);
}

__global__ __launch_bounds__(256) void k_scan(const int* __restrict__ cnt, int* __restrict__ offs){
  __shared__ int wsum[4], wbase[4];
  int t = threadIdx.x;
  int base = t * 8;
  int c[8]; int T = 0;
  #pragma unroll
  for (int i = 0; i < 8; i++){ c[i] = cnt[base + i]; T += c[i]; }
  int lane = t & 63, wv = t >> 6;
  int inc = T;
  #pragma unroll
  for (int st = 1; st < 64; st <<= 1){
    int v = __shfl_up(inc, st);
    if (lane >= st) inc += v;
  }
  if (lane == 63) wsum[wv] = inc;
  __syncthreads();
  if (t == 0){ int r = 0; for (int w2 = 0; w2 < 4; w2++){ wbase[w2] = r; r += wsum[w2]; } }
  __syncthreads();
  int run = wbase[wv] + inc - T;
  #pragma unroll
  for (int i = 0; i < 8; i++){ offs[base + i] = run; run += c[i]; }
  if (t == 255) offs[2048] = run;
}

__global__ __launch_bounds__(256) void k_scatter(const int* __restrict__ ei, const float* __restrict__ alpha,
    const int* __restrict__ offs, int* __restrict__ rk, int2* __restrict__ sidx, float* __restrict__ alphaS){
  int g = blockIdx.x * 256 + threadIdx.x;
  int i1, i2;
  if (g < EE){ i1 = ei[2*g]; i2 = ei[2*g + 1]; }
  else { int gg = g - EE; i1 = ei[2*gg + 1]; i2 = ei[2*gg]; }
  int r = atomicAdd(rk + i1, 1);
  int pos = offs[i1] + r;
  sidx[pos] = make_int2(i1, i2);
  alphaS[pos] = alpha[g];
}

__global__ __launch_bounds__(256) void k_dens(const int* __restrict__ offs, const float* __restrict__ alphaS,
                                              float* __restrict__ den){
  int n = blockIdx.x * 4 + (threadIdx.x >> 6);
  int lane = threadIdx.x & 63;
  int b = offs[n], e = offs[n + 1];
  float s = 0.f;
  for (int i = b + lane; i < e; i += 64) s += alphaS[i];
  #pragma unroll
  for (int st = 1; st < 64; st <<= 1) s += __shfl_xor(s, st);
  if (lane == 0) den[n] = s + (n == 0 ? 2048.f : 0.f);
}

// ---------------- MFMA tile helpers ----------------
template<int NT, int KS, int SR>
__device__ __forceinline__ void tile_gemm(const char* sm, int aBase, int bBase, int lane, f32x4* acc){
  const int r15 = lane & 15;
  const int kb = (lane >> 4) * 16;
  #pragma unroll
  for (int ks = 0; ks < KS; ks++){
    bf16x8 a = *(const bf16x8*)(sm + aBase + swzb(r15*SR + ks*64 + kb, r15));
    #pragma unroll
    for (int ct = 0; ct < NT; ct++){
      int n = ct*16 + r15;
      bf16x8 b = *(const bf16x8*)(sm + bBase + swzb(n*SR + ks*64 + kb, n));
      acc[ct] = __builtin_amdgcn_mfma_f32_16x16x32_bf16(a, b, acc[ct], 0, 0, 0);
    }
  }
}

// B directly from global (L2-hot weight pool), un-swizzled [Nc][Kp] bf16
template<int NT, int KS, int SR>
__device__ __forceinline__ void tile_gemm_gb(const char* sm, int aBase, const u16* __restrict__ W, int Kp,
                                             int lane, f32x4* acc){
  const int r15 = lane & 15;
  const int kb = (lane >> 4) * 16;
  const int ke = (lane >> 4) * 8;
  #pragma unroll
  for (int ks = 0; ks < KS; ks++){
    bf16x8 a = *(const bf16x8*)(sm + aBase + swzb(r15*SR + ks*64 + kb, r15));
    #pragma unroll
    for (int ct = 0; ct < NT; ct++){
      int n = ct*16 + r15;
      bf16x8 b = *(const bf16x8*)(W + n*Kp + ks*32 + ke);
      acc[ct] = __builtin_amdgcn_mfma_f32_16x16x32_bf16(a, b, acc[ct], 0, 0, 0);
    }
  }
}

// ---------------- generic GEMM: C[M][Nc] = act(A[M][K] @ W + bias), M mult of 64 ----------------
template<int NT, int KS, int ACT>
__global__ __launch_bounds__(256) void k_gemm(const float* __restrict__ A, int K,
    const u16* __restrict__ Wt, const float* __restrict__ bias, float* __restrict__ C)
{
  constexpr int Kpad = KS * 32;
  constexpr int Nc = NT * 16;
  constexpr int SR = (Kpad*2 + 127) / 128 * 128;
  constexpr int ABASE = Nc * SR;
  __shared__ __align__(16) char smem[Nc*SR + 64*SR];
  constexpr int KP8 = Kpad / 8;
  for (int j = threadIdx.x; j < Nc*KP8; j += 256){
    int n = j / KP8;
    *(uint4*)(smem + swzb(n*SR + (j - n*KP8)*16, n)) = ((const uint4*)Wt)[j];
  }
  const int row0 = blockIdx.x * 64;
  for (int j = threadIdx.x; j < 64*(Kpad/2); j += 256){
    int r = j / (Kpad/2); int c = (j - r*(Kpad/2)) * 2;
    const float* ap = A + (size_t)(row0 + r)*K + c;
    float f0 = (c < K) ? ap[0] : 0.f;
    float f1 = (c + 1 < K) ? ap[1] : 0.f;
    *(u32*)(smem + ABASE + swzb(r*SR + c*2, r)) = (u32)f2bf(f0) | ((u32)f2bf(f1) << 16);
  }
  __syncthreads();
  const int lane = threadIdx.x & 63, w = threadIdx.x >> 6;
  const int r15 = lane & 15;
  f32x4 acc[NT] = {};
  tile_gemm<NT, KS, SR>(smem, ABASE + w*16*SR, 0, lane, acc);
  #pragma unroll
  for (int ct = 0; ct < NT; ct++){
    int col = ct*16 + r15;
    float bs = bias[col];
    #pragma unroll
    for (int q = 0; q < 4; q++){
      int r = row0 + w*16 + (lane >> 4)*4 + q;
      float v = acc[ct][q] + bs;
      if (ACT == 1) v = lrelu(v);
      if (ACT == 2) v = v > 0.f ? v : 0.f;
      C[(size_t)r*Nc + col] = v;
    }
  }
}

// ---------------- LayerNorm(a+b), optional bf16 mirror ----------------
__global__ __launch_bounds__(256) void k_ln(const float* __restrict__ A, const float* __restrict__ B,
    const float* __restrict__ sc, const float* __restrict__ bi, float* __restrict__ out,
    u16* __restrict__ hbf)
{
  const int row = blockIdx.x*4 + (threadIdx.x >> 6);
  const int lane = threadIdx.x & 63;
  const float* ap = A + row*96; const float* bp = B + row*96;
  float v1 = ap[lane] + bp[lane];
  float v2 = (lane < 32) ? (ap[64+lane] + bp[64+lane]) : 0.f;
  float sum = v1 + v2, sq = v1*v1 + v2*v2;
  #pragma unroll
  for (int st = 1; st < 64; st <<= 1){ sum += __shfl_xor(sum, st); sq += __shfl_xor(sq, st); }
  float mean = sum * (1.f/96.f);
  float var = sq * (1.f/96.f) - mean*mean;
  float rs = rsqrtf(var + 1e-5f);
  float o1 = (v1 - mean)*rs*sc[lane] + bi[lane];
  out[row*96 + lane] = o1;
  if (hbf) hbf[row*96 + lane] = f2bf(o1);
  if (lane < 32){
    float o2 = (v2 - mean)*rs*sc[64+lane] + bi[64+lane];
    out[row*96 + 64 + lane] = o2;
    if (hbf) hbf[row*96 + 64 + lane] = f2bf(o2);
  }
}

// ---------------- attention v2: one q-row per lane, no-max softmax, uniform K/V from L2 ----------------
__global__ __launch_bounds__(256) void k_attn2(const float* __restrict__ qkv, float* __restrict__ obuf){
  __shared__ float part[4][64][13];   // stride 13 -> 2-way banks (free)
  const int tid = threadIdx.x;
  const int lane = tid & 63, w = tid >> 6;
  const int head = blockIdx.x >> 5, rb = blockIdx.x & 31;
  const int row = rb*64 + lane;
  const float* qp = qkv + (size_t)row*288 + head*8;
  float4 qa = *(const float4*)qp;
  float4 qb = *(const float4*)(qp + 4);
  const float* kv = qkv + 96 + head*8 + (size_t)(w*512)*288;
  float sm = 0.f;
  float o0=0,o1=0,o2=0,o3=0,o4=0,o5=0,o6=0,o7=0;
  #pragma unroll 4
  for (int j = 0; j < 512; j++){
    const float* kp = kv + (size_t)j*288;
    float4 ka = *(const float4*)kp;
    float4 kb = *(const float4*)(kp + 4);
    float4 va = *(const float4*)(kp + 96);
    float4 vb = *(const float4*)(kp + 100);
    float s = qa.x*ka.x + qa.y*ka.y + qa.z*ka.z + qa.w*ka.w
            + qb.x*kb.x + qb.y*kb.y + qb.z*kb.z + qb.w*kb.w;
    s = fminf(s * 0.35355339059327373f, 60.f);
    float p = __expf(s);
    sm += p;
    o0 += p*va.x; o1 += p*va.y; o2 += p*va.z; o3 += p*va.w;
    o4 += p*vb.x; o5 += p*vb.y; o6 += p*vb.z; o7 += p*vb.w;
  }
  float* pp = part[w][lane];
  pp[0]=o0; pp[1]=o1; pp[2]=o2; pp[3]=o3; pp[4]=o4; pp[5]=o5; pp[6]=o6; pp[7]=o7; pp[8]=sm;
  __syncthreads();
  if (w == 0){
    float t[9];
    #pragma unroll
    for (int d = 0; d < 9; d++)
      t[d] = part[0][lane][d] + part[1][lane][d] + part[2][lane][d] + part[3][lane][d];
    float inv = 1.f / t[8];
    float* op = obuf + (size_t)row*96 + head*8;
    #pragma unroll
    for (int d = 0; d < 8; d++) op[d] = t[d]*inv;
  }
}

// ---------------- fused edge MLPs: ef -> ein1 -> ein2 (efnn) -> {ad, ar} -> alpha ----------------
__global__ __launch_bounds__(256) void k_edge(const float* __restrict__ efr, const float* __restrict__ es,
    const u16* __restrict__ pool,
    const float* __restrict__ eb1, const float* __restrict__ eb2,
    const float* __restrict__ adb1, const float* __restrict__ adw2, const float* __restrict__ adb2,
    const float* __restrict__ arb1, const float* __restrict__ arw2, const float* __restrict__ arb2,
    u16* __restrict__ efnn, float* __restrict__ alpha)
{
  __shared__ __align__(16) char smem[49152];
  const int tid = threadIdx.x;
  const int e0 = blockIdx.x * 64;
  for (int j = tid; j < 256; j += 256){
    int n = j >> 2;
    *(uint4*)(smem + swzb(n*128 + (j&3)*16, n)) = ((const uint4*)(pool + EIN1T))[j];
  }
  for (int j = tid; j < 512; j += 256){
    int n = j >> 3; int b = n*128 + (j&7)*16;
    *(uint4*)(smem + 8192  + swzb(b, n)) = ((const uint4*)(pool + EIN2T))[j];
    *(uint4*)(smem + 16384 + swzb(b, n)) = ((const uint4*)(pool + AD1T))[j];
    *(uint4*)(smem + 24576 + swzb(b, n)) = ((const uint4*)(pool + AR1T))[j];
  }
  for (int j = tid; j < 64*16; j += 256){
    int r = j >> 4; int c = (j & 15) * 2;
    float f0 = 0.f, f1 = 0.f;
    if (c < 12)     f0 = (efr[(e0+r)*12 + c]     + 1e-4f) / es[c];
    if (c + 1 < 12) f1 = (efr[(e0+r)*12 + c + 1] + 1e-4f) / es[c+1];
    *(u32*)(smem + 32768 + swzb(r*128 + c*2, r)) = (u32)f2bf(f0) | ((u32)f2bf(f1) << 16);
  }
  __syncthreads();
  const int lane = tid & 63, w = tid >> 6;
  const int r15 = lane & 15;

  auto store_lds = [&](f32x4* acc, int base, const float* bias){
    #pragma unroll
    for (int ct = 0; ct < 4; ct++){
      int col = ct*16 + r15;
      float bs = bias[col];
      #pragma unroll
      for (int q = 0; q < 4; q++){
        int row = w*16 + (lane >> 4)*4 + q;
        *(u16*)(smem + base + swzb(row*128 + col*2, row)) = f2bf(lrelu(acc[ct][q] + bs));
      }
    }
  };

  { f32x4 acc[4] = {};
    tile_gemm<4,1,128>(smem, 32768 + w*2048, 0, lane, acc);
    store_lds(acc, 40960, eb1); }
  { f32x4 acc[4] = {};
    tile_gemm<4,2,128>(smem, 40960 + w*2048, 8192, lane, acc);
    store_lds(acc, 32768, eb2); }
  __syncthreads();
  for (int j = tid; j < 2048; j += 256){
    int r = j >> 5;
    ((u32*)efnn)[e0*32 + j] = *(const u32*)(smem + 32768 + swzb(r*128 + (j&31)*4, r));
  }
  { f32x4 acc[4] = {};
    tile_gemm<4,2,128>(smem, 32768 + w*2048, 16384, lane, acc);
    store_lds(acc, 40960, adb1); }
  __syncthreads();
  { int row = tid >> 2, part = tid & 3;
    float s = 0.f;
    #pragma unroll
    for (int i = 0; i < 16; i++){
      int k = part*16 + i;
      s += bf2f(*(const u16*)(smem + 40960 + swzb(row*128 + k*2, row))) * adw2[k];
    }
    s += __shfl_xor(s, 1); s += __shfl_xor(s, 2);
    if (part == 0) alpha[e0 + row] = 1.f / (1.f + __expf(-(s + adb2[0]))); }
  __syncthreads();
  { f32x4 acc[4] = {};
    tile_gemm<4,2,128>(smem, 32768 + w*2048, 24576, lane, acc);
    store_lds(acc, 40960, arb1); }
  __syncthreads();
  { int row = tid >> 2, part = tid & 3;
    float s = 0.f;
    #pragma unroll
    for (int i = 0; i < 16; i++){
      int k = part*16 + i;
      s += bf2f(*(const u16*)(smem + 40960 + swzb(row*128 + k*2, row))) * arw2[k];
    }
    s += __shfl_xor(s, 1); s += __shfl_xor(s, 2);
    if (part == 0) alpha[EE + e0 + row] = 1.f / (1.f + __expf(-(s + arb2[0]))); }
}

// ---------------- graph-conv over destination-sorted rows (gather -> MLP -> segment scan) ----------------
__global__ __launch_bounds__(256) void k_gc2(const u16* __restrict__ hbf, const int2* __restrict__ sidx,
    const float* __restrict__ alphaS, const u16* __restrict__ wt1, const u16* __restrict__ wt2,
    const float* __restrict__ b1, const float* __restrict__ b2, float* __restrict__ num)
{
  __shared__ __align__(16) char smem[51712];
  int*   nid  = (int*)(smem + 50176);
  int*   i2s  = (int*)(smem + 50688);
  float* alph = (float*)(smem + 51200);
  const int tid = threadIdx.x;
  const int row0 = blockIdx.x * 128;
  if (tid < 128){
    int2 p = sidx[row0 + tid];
    nid[tid] = p.x; i2s[tid] = p.y;
    alph[tid] = alphaS[row0 + tid];
  }
  __syncthreads();
  for (int j = tid; j < 128*24; j += 256){
    int r = j / 24, q = j - (j / 24)*24;
    int c8 = q * 8;
    int sr = (q < 12) ? nid[r] : i2s[r];
    int cc = (q < 12) ? c8 : c8 - 96;
    bf16x8 v = *(const bf16x8*)(hbf + sr*96 + cc);
    *(bf16x8*)(smem + swzb(r*384 + c8*2, r)) = v;
  }
  __syncthreads();
  const int lane = tid & 63, w = tid >> 6;
  const int wr = w >> 1, wc = w & 1;
  const int r15 = lane & 15;
  const int kb = (lane >> 4) * 16;
  const int ke = (lane >> 4) * 8;
  f32x4 acc[4][6] = {};
  #pragma unroll
  for (int ks = 0; ks < 6; ks++){
    bf16x8 a[4];
    #pragma unroll
    for (int rt = 0; rt < 4; rt++){
      int row = wr*64 + rt*16 + r15;
      a[rt] = *(const bf16x8*)(smem + swzb(row*384 + ks*64 + kb, row));
    }
    #pragma unroll
    for (int ct = 0; ct < 6; ct++){
      int n = wc*96 + ct*16 + r15;
      bf16x8 b = *(const bf16x8*)(wt1 + n*192 + ks*32 + ke);
      #pragma unroll
      for (int rt = 0; rt < 4; rt++)
        acc[rt][ct] = __builtin_amdgcn_mfma_f32_16x16x32_bf16(a[rt], b, acc[rt][ct], 0, 0, 0);
    }
  }
  __syncthreads();
  #pragma unroll
  for (int ct = 0; ct < 6; ct++){
    int col = wc*96 + ct*16 + r15;
    float bs = b1[col];
    #pragma unroll
    for (int rt = 0; rt < 4; rt++){
      #pragma unroll
      for (int q = 0; q < 4; q++){
        int row = wr*64 + rt*16 + (lane >> 4)*4 + q;
        *(u16*)(smem + swzb(row*384 + col*2, row)) = f2bf(lrelu(acc[rt][ct][q] + bs));
      }
    }
  }
  __syncthreads();
  f32x4 acc2[4][3] = {};
  #pragma unroll
  for (int ks = 0; ks < 6; ks++){
    bf16x8 a[4];
    #pragma unroll
    for (int rt = 0; rt < 4; rt++){
      int row = wr*64 + rt*16 + r15;
      a[rt] = *(const bf16x8*)(smem + swzb(row*384 + ks*64 + kb, row));
    }
    #pragma unroll
    for (int ct = 0; ct < 3; ct++){
      int n = wc*48 + ct*16 + r15;
      bf16x8 b = *(const bf16x8*)(wt2 + n*192 + ks*32 + ke);
      #pragma unroll
      for (int rt = 0; rt < 4; rt++)
        acc2[rt][ct] = __builtin_amdgcn_mfma_f32_16x16x32_bf16(a[rt], b, acc2[rt][ct], 0, 0, 0);
    }
  }
  __syncthreads();
  #pragma unroll
  for (int ct = 0; ct < 3; ct++){
    int col = wc*48 + ct*16 + r15;
    float bs = b2[col];
    #pragma unroll
    for (int rt = 0; rt < 4; rt++){
      #pragma unroll
      for (int q = 0; q < 4; q++){
        int row = wr*64 + rt*16 + (lane >> 4)*4 + q;
        *(float*)(smem + row*392 + col*4) = alph[row] * lrelu(acc2[rt][ct][q] + bs);
      }
    }
  }
  __syncthreads();
  if (tid < 192){
    int hf = tid / 96;
    int c = tid - hf*96;
    int rbeg = hf*64, rend = rbeg + 64;
    float accv = 0.f;
    int cur = nid[rbeg];
    for (int r = rbeg; r < rend; r++){
      int n2 = nid[r];
      if (n2 != cur){ atomicAdd(num + cur*96 + c, accv); accv = 0.f; cur = n2; }
      accv += *(const float*)(smem + r*392 + c*4);
    }
    atomicAdd(num + cur*96 + c, accv);
  }
}

// the N rows with ind1=ind2=0 are identical: compute once, add 2048x
__global__ __launch_bounds__(256) void k_gcnode0(const float* __restrict__ h,
    const float* __restrict__ W1, const float* __restrict__ b1,
    const float* __restrict__ W2, const float* __restrict__ b2, float* __restrict__ num)
{
  __shared__ float in_s[192], h1_s[192];
  int t = threadIdx.x;
  if (t < 192) in_s[t] = h[t % 96];
  __syncthreads();
  if (t < 192){
    float s = b1[t];
    for (int k = 0; k < 192; k++) s += in_s[k] * W1[k*192 + t];
    h1_s[t] = lrelu(s);
  }
  __syncthreads();
  if (t < 96){
    float s = b2[t];
    for (int k = 0; k < 192; k++) s += h1_s[k] * W2[k*96 + t];
    num[t] += 2048.f * lrelu(s);
  }
}

__global__ __launch_bounds__(256) void k_hupd(const float* __restrict__ num, const float* __restrict__ den,
                                              float* __restrict__ h, u16* __restrict__ hbf){
  int i = blockIdx.x * 256 + threadIdx.x;
  float v = num[i] / (den[i / 96] + 1e-8f);
  h[i] = v;
  hbf[i] = f2bf(v);
}

// ---------------- final per-edge predictor ----------------
__global__ __launch_bounds__(256) void k_final(const u16* __restrict__ hbf, const int* __restrict__ ei,
    const u16* __restrict__ efnn, const float* __restrict__ efr, const float* __restrict__ es,
    const u16* __restrict__ en1, const float* __restrict__ enb1,
    const float* __restrict__ enw2, const float* __restrict__ enb2, float* __restrict__ out)
{
  __shared__ __align__(16) char smem[65792];
  const int tid = threadIdx.x;
  const int e0 = blockIdx.x * 64;
  for (int j = tid; j < 64*36; j += 256){
    int r = j / 36, q = j - (j / 36)*36;
    int e = e0 + r;
    if (q < 32){
      bf16x8 v;
      if (q < 24){
        int idx = (q < 12) ? ei[2*e] : ei[2*e + 1];
        int cc = (q < 12) ? q*8 : q*8 - 96;
        v = *(const bf16x8*)(hbf + idx*96 + cc);
      } else {
        v = *(const bf16x8*)(efnn + e*64 + (q - 24)*8);
      }
      *(bf16x8*)(smem + swzb(r*640 + q*16, r)) = v;
    } else {
      u16 pk[8];
      int c0 = 256 + (q - 32)*8;
      #pragma unroll
      for (int i = 0; i < 8; i++){
        int cc = c0 + i - 256;
        pk[i] = (cc < 12) ? f2bf((efr[e*12 + cc] + 1e-4f) / es[cc]) : (u16)0;
      }
      *(bf16x8*)(smem + swzb(r*640 + c0*2, r)) = *(bf16x8*)pk;
    }
  }
  __syncthreads();
  const int lane = tid & 63, w = tid >> 6;
  const int r15 = lane & 15;
  f32x4 acc[6] = {};
  tile_gemm_gb<6,9,640>(smem, w*10240, en1, 288, lane, acc);
  #pragma unroll
  for (int ct = 0; ct < 6; ct++){
    int col = ct*16 + r15;
    float bs = enb1[col];
    #pragma unroll
    for (int q = 0; q < 4; q++){
      int row = w*16 + (lane >> 4)*4 + q;
      *(float*)(smem + 40960 + (row*97 + col)*4) = lrelu(acc[ct][q] + bs);
    }
  }
  __syncthreads();
  int row = tid >> 2, part = tid & 3;
  float s = 0.f;
  #pragma unroll
  for (int i = 0; i < 24; i++){
    int k = part*24 + i;
    s += *(const float*)(smem + 40960 + (row*97 + k)*4) * enw2[k];
  }
  s += __shfl_xor(s, 1); s += __shfl_xor(s, 2);
  if (part == 0) out[e0 + row] = 1.f / (1.f + __expf(-(s + enb2[0])));
}

// ---------------- host ----------------
extern "C" void kernel_launch(void* const* d_in, const int* in_sizes, int n_in,
                              void* d_out, int out_size, void* d_ws, size_t ws_size,
                              hipStream_t stream) {
  (void)in_sizes; (void)n_in; (void)out_size; (void)ws_size;
  const float* X      = (const float*)d_in[0];
  const float* EFR    = (const float*)d_in[1];
  const int*   EI     = (const int*)  d_in[2];
  const float* NS     = (const float*)d_in[3];
  const float* ES     = (const float*)d_in[4];
  const float* IN_W1  = (const float*)d_in[5];
  const float* IN_B1  = (const float*)d_in[6];
  const float* IN_W2  = (const float*)d_in[7];
  const float* IN_B2  = (const float*)d_in[8];
  const float* QKV_W  = (const float*)d_in[9];
  const float* QKV_B  = (const float*)d_in[10];
  const float* OUT_W  = (const float*)d_in[11];
  const float* OUT_B  = (const float*)d_in[12];
  const float* LN1S   = (const float*)d_in[13];
  const float* LN1B   = (const float*)d_in[14];
  const float* FFW1   = (const float*)d_in[15];
  const float* FFB1   = (const float*)d_in[16];
  const float* FFW2   = (const float*)d_in[17];
  const float* FFB2   = (const float*)d_in[18];
  const float* LN2S   = (const float*)d_in[19];
  const float* LN2B   = (const float*)d_in[20];
  const float* EIN_W1 = (const float*)d_in[21];
  const float* EIN_B1 = (const float*)d_in[22];
  const float* EIN_W2 = (const float*)d_in[23];
  const float* EIN_B2 = (const float*)d_in[24];
  const float* AD_W1  = (const float*)d_in[25];
  const float* AD_B1  = (const float*)d_in[26];
  const float* AD_W2  = (const float*)d_in[27];
  const float* AD_B2  = (const float*)d_in[28];
  const float* AR_W1  = (const float*)d_in[29];
  const float* AR_B1  = (const float*)d_in[30];
  const float* AR_W2  = (const float*)d_in[31];
  const float* AR_B2  = (const float*)d_in[32];
  const float* GC_W1  = (const float*)d_in[33];
  const float* GC_B1  = (const float*)d_in[34];
  const float* GC_W2  = (const float*)d_in[35];
  const float* GC_B2  = (const float*)d_in[36];
  const float* EN_W1  = (const float*)d_in[37];
  const float* EN_B1  = (const float*)d_in[38];
  const float* EN_W2  = (const float*)d_in[39];
  const float* EN_B2  = (const float*)d_in[40];

  char* ws = (char*)d_ws;
  u16*   pool   = (u16*)  (ws + WS_WT);
  u16*   efnn   = (u16*)  (ws + WS_EFNN);
  float* alpha  = (float*)(ws + WS_ALPHA);
  float* h      = (float*)(ws + WS_H);
  float* qkvb   = (float*)(ws + WS_QKV);
  float* obuf   = (float*)(ws + WS_OBUF);
  float* tmpA   = (float*)(ws + WS_TMPA);
  float* tmpB   = (float*)(ws + WS_TMPB);
  float* x1     = (float*)(ws + WS_X1);
  float* num    = (float*)(ws + WS_NUM);
  float* den    = (float*)(ws + WS_DEN);
  float* xs     = (float*)(ws + WS_XS);
  u16*   hbf    = (u16*)  (ws + WS_HBF);
  int2*  sidx   = (int2*) (ws + WS_SIDX);
  float* alphaS = (float*)(ws + WS_ALPS);
  int*   cnt    = (int*)  (ws + WS_CNT);
  int*   offs   = (int*)  (ws + WS_OFFS);

  // ---- weight conversion jobs ----
  CvtJobs jb;
  int idx = 0, cum = 0;
  auto addjob = [&](const float* s, int K, int Nc, int Kp){
    jb.src[idx] = s; jb.K[idx] = K; jb.Nc[idx] = Nc; jb.Kp[idx] = Kp;
    jb.cum[idx] = cum; cum += Nc * Kp; idx++;
  };
  addjob(IN_W1, 19, 96, 32);
  addjob(IN_W2, 96, 96, 96);
  for (int l = 0; l < 3; l++) addjob(QKV_W + (size_t)l*96*288, 96, 288, 96);
  for (int l = 0; l < 3; l++) addjob(OUT_W + (size_t)l*96*96,  96, 96,  96);
  for (int l = 0; l < 3; l++) addjob(FFW1  + (size_t)l*96*192, 96, 192, 96);
  for (int l = 0; l < 3; l++) addjob(FFW2  + (size_t)l*192*96, 192, 96, 192);
  addjob(EIN_W1, 12, 64, 32);
  addjob(EIN_W2, 64, 64, 64);
  addjob(AD_W1,  64, 64, 64);
  addjob(AR_W1,  64, 64, 64);
  for (int i = 0; i < 2; i++) addjob(GC_W1 + (size_t)i*192*192, 192, 192, 192);
  for (int i = 0; i < 2; i++) addjob(GC_W2 + (size_t)i*192*96,  192, 96,  192);
  addjob(EN_W1, 268, 96, 288);
  jb.cum[idx] = cum;

  k_cvt<<<(POOL_TOT + 255)/256, 256, 0, stream>>>(jb, pool);

  // ---- node embedding ----
  k_xscale<<<(NN*19 + 255)/256, 256, 0, stream>>>(X, NS, xs);
  k_gemm<6,1,1><<<32, 256, 0, stream>>>(xs, 19, pool + IN1T, IN_B1, tmpA);
  k_gemm<6,3,1><<<32, 256, 0, stream>>>(tmpA, 96, pool + IN2T, IN_B2, h);

  // ---- edge MLPs + attention weights ----
  k_edge<<<EE/64, 256, 0, stream>>>(EFR, ES, pool, EIN_B1, EIN_B2,
                                    AD_B1, AD_W2, AD_B2, AR_B1, AR_W2, AR_B2, efnn, alpha);

  // ---- destination sort + den ----
  (void)hipMemsetAsync(cnt, 0, NN*4, stream);
  k_hist<<<(2*EE)/256, 256, 0, stream>>>(EI, cnt);
  k_scan<<<1, 256, 0, stream>>>(cnt, offs);
  (void)hipMemsetAsync(cnt, 0, NN*4, stream);
  k_scatter<<<(2*EE)/256, 256, 0, stream>>>(EI, alpha, offs, cnt, sidx, alphaS);
  k_dens<<<NN/4, 256, 0, stream>>>(offs, alphaS, den);

  // ---- 3 encoder layers ----
  for (int l = 0; l < 3; l++){
    k_gemm<18,3,0><<<32, 256, 0, stream>>>(h, 96, pool + QKVT + l*27648, QKV_B + l*288, qkvb);
    k_attn2<<<384, 256, 0, stream>>>(qkvb, obuf);
    k_gemm<6,3,0><<<32, 256, 0, stream>>>(obuf, 96, pool + OUTT + l*9216, OUT_B + l*96, tmpA);
    k_ln<<<512, 256, 0, stream>>>(h, tmpA, LN1S + l*96, LN1B + l*96, x1, nullptr);
    k_gemm<12,3,2><<<32, 256, 0, stream>>>(x1, 96, pool + FF1T + l*18432, FFB1 + l*192, tmpB);
    k_gemm<6,6,0><<<32, 256, 0, stream>>>(tmpB, 192, pool + FF2T + l*18432, FFB2 + l*96, tmpA);
    k_ln<<<512, 256, 0, stream>>>(x1, tmpA, LN2S + l*96, LN2B + l*96, h, (l == 2) ? hbf : nullptr);
  }

  // ---- 2 graph-conv iterations ----
  for (int it = 0; it < 2; it++){
    (void)hipMemsetAsync(num, 0, NN*96*4, stream);
    k_gc2<<<(2*EE)/128, 256, 0, stream>>>(hbf, sidx, alphaS,
        pool + GC1T + it*36864, pool + GC2T + it*18432,
        GC_B1 + it*192, GC_B2 + it*96, num);
    k_gcnode0<<<1, 256, 0, stream>>>(h, GC_W1 + (size_t)it*192*192, GC_B1 + it*192,
                                     GC_W2 + (size_t)it*192*96, GC_B2 + it*96, num);
    k_hupd<<<(NN*96)/256, 256, 0, stream>>>(num, den, h, hbf);
  }

  // ---- final predictor ----
  k_final<<<EE/64, 256, 0, stream>>>(hbf, EI, efnn, EFR, ES,
                                     pool + EN1T, EN_B1, EN_W2, EN_B2, (float*)d_out);
}

// Round 4
// 1021.136 us; speedup vs baseline: 2.5128x; 1.2890x over previous
//
#include <hip/hip_runtime.h>

// ---------------- constants ----------------
#define NN 2048
#define EE 262144

typedef __attribute__((ext_vector_type(8))) short bf16x8;
typedef __attribute__((ext_vector_type(4))) float f32x4;
typedef unsigned int u32;
typedef unsigned short u16;

__device__ __forceinline__ u16 f2bf(float f){
  u32 u = __builtin_bit_cast(u32, f);
  u32 r = u + 0x7FFFu + ((u >> 16) & 1u);
  return (u16)(r >> 16);
}
__device__ __forceinline__ float bf2f(u16 h){
  u32 u = ((u32)h) << 16;
  return __builtin_bit_cast(float, u);
}
__device__ __forceinline__ int swzb(int byte, int row){ return byte ^ ((row & 7) << 4); }
__device__ __forceinline__ float lrelu(float v){ return v > 0.f ? v : 0.01f * v; }

// ---------------- ws layout (bytes) ----------------
static const size_t WS_WT    = 0;                    // u16 pool (772096 B)
static const size_t WS_EFNN  = 772096;               // u16 E*64
static const size_t WS_ALPHA = WS_EFNN  + 33554432;  // f32 2E  (a_dir | a_rev)
static const size_t WS_H     = WS_ALPHA + 2097152;   // f32 N*96
static const size_t WS_QKV   = WS_H     + 786432;    // f32 N*288 ; P1 reuses this
static const size_t WS_OBUF  = WS_QKV   + 2359296;   // f32 N*96  ; hp1 reuses this
static const size_t WS_TMPA  = WS_OBUF  + 786432;    // f32 N*96  ; hp2 reuses this
static const size_t WS_TMPB  = WS_TMPA  + 786432;    // f32 N*192 ; P2 reuses this
static const size_t WS_X1    = WS_TMPB  + 1572864;   // f32 N*96
static const size_t WS_NUM   = WS_X1    + 786432;    // f32 N*96
static const size_t WS_DEN   = WS_NUM   + 786432;    // f32 N (pad)
static const size_t WS_XS    = WS_DEN   + 8192;      // f32 N*19 (pad)
static const size_t WS_HBF   = WS_XS    + 155648;    // (dead)
static const size_t WS_SIDX  = WS_HBF   + 393216;    // int2 2E
static const size_t WS_ALPS  = WS_SIDX  + 4194304;   // f32 2E (sorted alpha)
static const size_t WS_CNT   = WS_ALPS  + 2097152;   // int N
static const size_t WS_OFFS  = WS_CNT   + 8192;      // int N+1 (pad)

// pool element offsets (bf16, weights transposed [Nc][Kpad])
#define IN1T 0
#define IN2T 3072
#define QKVT 12288
#define OUTT 95232
#define FF1T 122880
#define FF2T 178176
#define EIN1T 233472
#define EIN2T 235520
#define AD1T 239616
#define AR1T 243712
#define GC1T 247808
#define GC2T 321536
#define ENAT 358400
#define ENBT 367616
#define ENCT 376832
#define POOL_TOT 386048

// ---------------- weight convert (f32 -> bf16, transposed, K-padded) ----------------
struct CvtJobs {
  const float* src[27];
  int K[27], Nc[27], Kp[27];
  int cum[28];
};

__global__ __launch_bounds__(256) void k_cvt(CvtJobs jb, u16* __restrict__ pool){
  int i = blockIdx.x * 256 + threadIdx.x;
  if (i >= jb.cum[27]) return;
  int j = 0;
  while (i >= jb.cum[j + 1]) j++;
  int loc = i - jb.cum[j];
  int Kp = jb.Kp[j];
  int n = loc / Kp, k = loc - n * Kp;
  float v = (k < jb.K[j]) ? jb.src[j][(size_t)k * jb.Nc[j] + n] : 0.f;
  pool[i] = f2bf(v);
}

__global__ __launch_bounds__(256) void k_xscale(const float* __restrict__ X, const float* __restrict__ ns,
                                                float* __restrict__ xs){
  int i = blockIdx.x * 256 + threadIdx.x;
  if (i < NN * 19) xs[i] = X[i] / ns[i % 19];
}

// ---------------- destination sort (counting sort over 2E edge rows) ----------------
__global__ __launch_bounds__(256) void k_hist(const int* __restrict__ ei, int* __restrict__ cnt){
  int g = blockIdx.x * 256 + threadIdx.x;
  int i1 = (g < EE) ? ei[2*g] : ei[2*(g - EE) + 1];
  atomicAdd(cnt + i1, 1);
}

__global__ __launch_bounds__(256) void k_scan(const int* __restrict__ cnt, int* __restrict__ offs){
  __shared__ int wsum[4], wbase[4];
  int t = threadIdx.x;
  int base = t * 8;
  int c[8]; int T = 0;
  #pragma unroll
  for (int i = 0; i < 8; i++){ c[i] = cnt[base + i]; T += c[i]; }
  int lane = t & 63, wv = t >> 6;
  int inc = T;
  #pragma unroll
  for (int st = 1; st < 64; st <<= 1){
    int v = __shfl_up(inc, st);
    if (lane >= st) inc += v;
  }
  if (lane == 63) wsum[wv] = inc;
  __syncthreads();
  if (t == 0){ int r = 0; for (int w2 = 0; w2 < 4; w2++){ wbase[w2] = r; r += wsum[w2]; } }
  __syncthreads();
  int run = wbase[wv] + inc - T;
  #pragma unroll
  for (int i = 0; i < 8; i++){ offs[base + i] = run; run += c[i]; }
  if (t == 255) offs[2048] = run;
}

__global__ __launch_bounds__(256) void k_scatter(const int* __restrict__ ei, const float* __restrict__ alpha,
    const int* __restrict__ offs, int* __restrict__ rk, int2* __restrict__ sidx, float* __restrict__ alphaS){
  int g = blockIdx.x * 256 + threadIdx.x;
  int i1, i2;
  if (g < EE){ i1 = ei[2*g]; i2 = ei[2*g + 1]; }
  else { int gg = g - EE; i1 = ei[2*gg + 1]; i2 = ei[2*gg]; }
  int r = atomicAdd(rk + i1, 1);
  int pos = offs[i1] + r;
  sidx[pos] = make_int2(i1, i2);
  alphaS[pos] = alpha[g];
}

__global__ __launch_bounds__(256) void k_dens(const int* __restrict__ offs, const float* __restrict__ alphaS,
                                              float* __restrict__ den){
  int n = blockIdx.x * 4 + (threadIdx.x >> 6);
  int lane = threadIdx.x & 63;
  int b = offs[n], e = offs[n + 1];
  float s = 0.f;
  for (int i = b + lane; i < e; i += 64) s += alphaS[i];
  #pragma unroll
  for (int st = 1; st < 64; st <<= 1) s += __shfl_xor(s, st);
  if (lane == 0) den[n] = s + (n == 0 ? 2048.f : 0.f);
}

// ---------------- MFMA tile helpers ----------------
template<int NT, int KS, int SR>
__device__ __forceinline__ void tile_gemm(const char* sm, int aBase, int bBase, int lane, f32x4* acc){
  const int r15 = lane & 15;
  const int kb = (lane >> 4) * 16;
  #pragma unroll
  for (int ks = 0; ks < KS; ks++){
    bf16x8 a = *(const bf16x8*)(sm + aBase + swzb(r15*SR + ks*64 + kb, r15));
    #pragma unroll
    for (int ct = 0; ct < NT; ct++){
      int n = ct*16 + r15;
      bf16x8 b = *(const bf16x8*)(sm + bBase + swzb(n*SR + ks*64 + kb, n));
      acc[ct] = __builtin_amdgcn_mfma_f32_16x16x32_bf16(a, b, acc[ct], 0, 0, 0);
    }
  }
}

// B directly from global (L2-hot weight pool), un-swizzled [Nc][Kp] bf16
template<int NT, int KS, int SR>
__device__ __forceinline__ void tile_gemm_gb(const char* sm, int aBase, const u16* __restrict__ W, int Kp,
                                             int lane, f32x4* acc){
  const int r15 = lane & 15;
  const int kb = (lane >> 4) * 16;
  const int ke = (lane >> 4) * 8;
  #pragma unroll
  for (int ks = 0; ks < KS; ks++){
    bf16x8 a = *(const bf16x8*)(sm + aBase + swzb(r15*SR + ks*64 + kb, r15));
    #pragma unroll
    for (int ct = 0; ct < NT; ct++){
      int n = ct*16 + r15;
      bf16x8 b = *(const bf16x8*)(W + n*Kp + ks*32 + ke);
      acc[ct] = __builtin_amdgcn_mfma_f32_16x16x32_bf16(a, b, acc[ct], 0, 0, 0);
    }
  }
}

// ---------------- generic GEMM: C[M][Nc] = act(A[M][K] @ W + bias), M mult of 64 ----------------
template<int NT, int KS, int ACT>
__global__ __launch_bounds__(256) void k_gemm(const float* __restrict__ A, int K,
    const u16* __restrict__ Wt, const float* __restrict__ bias, float* __restrict__ C)
{
  constexpr int Kpad = KS * 32;
  constexpr int Nc = NT * 16;
  constexpr int SR = (Kpad*2 + 127) / 128 * 128;
  constexpr int ABASE = Nc * SR;
  __shared__ __align__(16) char smem[Nc*SR + 64*SR];
  constexpr int KP8 = Kpad / 8;
  for (int j = threadIdx.x; j < Nc*KP8; j += 256){
    int n = j / KP8;
    *(uint4*)(smem + swzb(n*SR + (j - n*KP8)*16, n)) = ((const uint4*)Wt)[j];
  }
  const int row0 = blockIdx.x * 64;
  for (int j = threadIdx.x; j < 64*(Kpad/2); j += 256){
    int r = j / (Kpad/2); int c = (j - r*(Kpad/2)) * 2;
    const float* ap = A + (size_t)(row0 + r)*K + c;
    float f0 = (c < K) ? ap[0] : 0.f;
    float f1 = (c + 1 < K) ? ap[1] : 0.f;
    *(u32*)(smem + ABASE + swzb(r*SR + c*2, r)) = (u32)f2bf(f0) | ((u32)f2bf(f1) << 16);
  }
  __syncthreads();
  const int lane = threadIdx.x & 63, w = threadIdx.x >> 6;
  const int r15 = lane & 15;
  f32x4 acc[NT] = {};
  tile_gemm<NT, KS, SR>(smem, ABASE + w*16*SR, 0, lane, acc);
  #pragma unroll
  for (int ct = 0; ct < NT; ct++){
    int col = ct*16 + r15;
    float bs = bias ? bias[col] : 0.f;
    #pragma unroll
    for (int q = 0; q < 4; q++){
      int r = row0 + w*16 + (lane >> 4)*4 + q;
      float v = acc[ct][q] + bs;
      if (ACT == 1) v = lrelu(v);
      if (ACT == 2) v = v > 0.f ? v : 0.f;
      C[(size_t)r*Nc + col] = v;
    }
  }
}

// ---------------- LayerNorm(a+b) ----------------
__global__ __launch_bounds__(256) void k_ln(const float* __restrict__ A, const float* __restrict__ B,
    const float* __restrict__ sc, const float* __restrict__ bi, float* __restrict__ out)
{
  const int row = blockIdx.x*4 + (threadIdx.x >> 6);
  const int lane = threadIdx.x & 63;
  const float* ap = A + row*96; const float* bp = B + row*96;
  float v1 = ap[lane] + bp[lane];
  float v2 = (lane < 32) ? (ap[64+lane] + bp[64+lane]) : 0.f;
  float sum = v1 + v2, sq = v1*v1 + v2*v2;
  #pragma unroll
  for (int st = 1; st < 64; st <<= 1){ sum += __shfl_xor(sum, st); sq += __shfl_xor(sq, st); }
  float mean = sum * (1.f/96.f);
  float var = sq * (1.f/96.f) - mean*mean;
  float rs = rsqrtf(var + 1e-5f);
  out[row*96 + lane] = (v1 - mean)*rs*sc[lane] + bi[lane];
  if (lane < 32) out[row*96 + 64 + lane] = (v2 - mean)*rs*sc[64+lane] + bi[64+lane];
}

// ---------------- attention v2: one q-row per lane, no-max softmax, uniform K/V from L2 ----------------
__global__ __launch_bounds__(256) void k_attn2(const float* __restrict__ qkv, float* __restrict__ obuf){
  __shared__ float part[4][64][13];
  const int tid = threadIdx.x;
  const int lane = tid & 63, w = tid >> 6;
  const int head = blockIdx.x >> 5, rb = blockIdx.x & 31;
  const int row = rb*64 + lane;
  const float* qp = qkv + (size_t)row*288 + head*8;
  float4 qa = *(const float4*)qp;
  float4 qb = *(const float4*)(qp + 4);
  const float* kv = qkv + 96 + head*8 + (size_t)(w*512)*288;
  float sm = 0.f;
  float o0=0,o1=0,o2=0,o3=0,o4=0,o5=0,o6=0,o7=0;
  #pragma unroll 4
  for (int j = 0; j < 512; j++){
    const float* kp = kv + (size_t)j*288;
    float4 ka = *(const float4*)kp;
    float4 kb = *(const float4*)(kp + 4);
    float4 va = *(const float4*)(kp + 96);
    float4 vb = *(const float4*)(kp + 100);
    float s = qa.x*ka.x + qa.y*ka.y + qa.z*ka.z + qa.w*ka.w
            + qb.x*kb.x + qb.y*kb.y + qb.z*kb.z + qb.w*kb.w;
    s = fminf(s * 0.35355339059327373f, 60.f);
    float p = __expf(s);
    sm += p;
    o0 += p*va.x; o1 += p*va.y; o2 += p*va.z; o3 += p*va.w;
    o4 += p*vb.x; o5 += p*vb.y; o6 += p*vb.z; o7 += p*vb.w;
  }
  float* pp = part[w][lane];
  pp[0]=o0; pp[1]=o1; pp[2]=o2; pp[3]=o3; pp[4]=o4; pp[5]=o5; pp[6]=o6; pp[7]=o7; pp[8]=sm;
  __syncthreads();
  if (w == 0){
    float t[9];
    #pragma unroll
    for (int d = 0; d < 9; d++)
      t[d] = part[0][lane][d] + part[1][lane][d] + part[2][lane][d] + part[3][lane][d];
    float inv = 1.f / t[8];
    float* op = obuf + (size_t)row*96 + head*8;
    #pragma unroll
    for (int d = 0; d < 8; d++) op[d] = t[d]*inv;
  }
}

// ---------------- fused edge MLPs: ef -> ein1 -> ein2 (efnn) -> {ad, ar} -> alpha ----------------
__global__ __launch_bounds__(256) void k_edge(const float* __restrict__ efr, const float* __restrict__ es,
    const u16* __restrict__ pool,
    const float* __restrict__ eb1, const float* __restrict__ eb2,
    const float* __restrict__ adb1, const float* __restrict__ adw2, const float* __restrict__ adb2,
    const float* __restrict__ arb1, const float* __restrict__ arw2, const float* __restrict__ arb2,
    u16* __restrict__ efnn, float* __restrict__ alpha)
{
  __shared__ __align__(16) char smem[49152];
  const int tid = threadIdx.x;
  const int e0 = blockIdx.x * 64;
  for (int j = tid; j < 256; j += 256){
    int n = j >> 2;
    *(uint4*)(smem + swzb(n*128 + (j&3)*16, n)) = ((const uint4*)(pool + EIN1T))[j];
  }
  for (int j = tid; j < 512; j += 256){
    int n = j >> 3; int b = n*128 + (j&7)*16;
    *(uint4*)(smem + 8192  + swzb(b, n)) = ((const uint4*)(pool + EIN2T))[j];
    *(uint4*)(smem + 16384 + swzb(b, n)) = ((const uint4*)(pool + AD1T))[j];
    *(uint4*)(smem + 24576 + swzb(b, n)) = ((const uint4*)(pool + AR1T))[j];
  }
  for (int j = tid; j < 64*16; j += 256){
    int r = j >> 4; int c = (j & 15) * 2;
    float f0 = 0.f, f1 = 0.f;
    if (c < 12)     f0 = (efr[(e0+r)*12 + c]     + 1e-4f) / es[c];
    if (c + 1 < 12) f1 = (efr[(e0+r)*12 + c + 1] + 1e-4f) / es[c+1];
    *(u32*)(smem + 32768 + swzb(r*128 + c*2, r)) = (u32)f2bf(f0) | ((u32)f2bf(f1) << 16);
  }
  __syncthreads();
  const int lane = tid & 63, w = tid >> 6;
  const int r15 = lane & 15;

  auto store_lds = [&](f32x4* acc, int base, const float* bias){
    #pragma unroll
    for (int ct = 0; ct < 4; ct++){
      int col = ct*16 + r15;
      float bs = bias[col];
      #pragma unroll
      for (int q = 0; q < 4; q++){
        int row = w*16 + (lane >> 4)*4 + q;
        *(u16*)(smem + base + swzb(row*128 + col*2, row)) = f2bf(lrelu(acc[ct][q] + bs));
      }
    }
  };

  { f32x4 acc[4] = {};
    tile_gemm<4,1,128>(smem, 32768 + w*2048, 0, lane, acc);
    store_lds(acc, 40960, eb1); }
  { f32x4 acc[4] = {};
    tile_gemm<4,2,128>(smem, 40960 + w*2048, 8192, lane, acc);
    store_lds(acc, 32768, eb2); }
  __syncthreads();
  for (int j = tid; j < 2048; j += 256){
    int r = j >> 5;
    ((u32*)efnn)[e0*32 + j] = *(const u32*)(smem + 32768 + swzb(r*128 + (j&31)*4, r));
  }
  { f32x4 acc[4] = {};
    tile_gemm<4,2,128>(smem, 32768 + w*2048, 16384, lane, acc);
    store_lds(acc, 40960, adb1); }
  __syncthreads();
  { int row = tid >> 2, part = tid & 3;
    float s = 0.f;
    #pragma unroll
    for (int i = 0; i < 16; i++){
      int k = part*16 + i;
      s += bf2f(*(const u16*)(smem + 40960 + swzb(row*128 + k*2, row))) * adw2[k];
    }
    s += __shfl_xor(s, 1); s += __shfl_xor(s, 2);
    if (part == 0) alpha[e0 + row] = 1.f / (1.f + __expf(-(s + adb2[0]))); }
  __syncthreads();
  { f32x4 acc[4] = {};
    tile_gemm<4,2,128>(smem, 32768 + w*2048, 24576, lane, acc);
    store_lds(acc, 40960, arb1); }
  __syncthreads();
  { int row = tid >> 2, part = tid & 3;
    float s = 0.f;
    #pragma unroll
    for (int i = 0; i < 16; i++){
      int k = part*16 + i;
      s += bf2f(*(const u16*)(smem + 40960 + swzb(row*128 + k*2, row))) * arw2[k];
    }
    s += __shfl_xor(s, 1); s += __shfl_xor(s, 2);
    if (part == 0) alpha[EE + e0 + row] = 1.f / (1.f + __expf(-(s + arb2[0]))); }
}

// ---------------- graph-conv v3: h1 = lrelu(P1[i1]+P2[i2]) -> GEMM2 -> segment scan ----------------
__global__ __launch_bounds__(256) void k_gc3(const float* __restrict__ P1, const float* __restrict__ P2,
    const int2* __restrict__ sidx, const float* __restrict__ alphaS, const u16* __restrict__ wt2,
    const float* __restrict__ b2, float* __restrict__ num)
{
  __shared__ __align__(16) char smem[51712];
  int*   nid  = (int*)(smem + 50176);
  int*   i2s  = (int*)(smem + 50688);
  float* alph = (float*)(smem + 51200);
  const int tid = threadIdx.x;
  const int row0 = blockIdx.x * 128;
  if (tid < 128){
    int2 p = sidx[row0 + tid];
    nid[tid] = p.x; i2s[tid] = p.y;
    alph[tid] = alphaS[row0 + tid];
  }
  __syncthreads();
  // h1 = lrelu(P1[i1] + P2[i2]) -> LDS bf16 [128][384B swz]
  for (int j = tid; j < 128*24; j += 256){
    int r = j / 24, q = j - (j/24)*24;
    int c8 = q * 8;
    const float* p1 = P1 + (size_t)nid[r]*192 + c8;
    const float* p2 = P2 + (size_t)i2s[r]*192 + c8;
    float4 a0 = *(const float4*)p1, a1 = *(const float4*)(p1 + 4);
    float4 b0 = *(const float4*)p2, b1 = *(const float4*)(p2 + 4);
    u16 pk[8];
    pk[0]=f2bf(lrelu(a0.x+b0.x)); pk[1]=f2bf(lrelu(a0.y+b0.y));
    pk[2]=f2bf(lrelu(a0.z+b0.z)); pk[3]=f2bf(lrelu(a0.w+b0.w));
    pk[4]=f2bf(lrelu(a1.x+b1.x)); pk[5]=f2bf(lrelu(a1.y+b1.y));
    pk[6]=f2bf(lrelu(a1.z+b1.z)); pk[7]=f2bf(lrelu(a1.w+b1.w));
    *(bf16x8*)(smem + swzb(r*384 + c8*2, r)) = *(bf16x8*)pk;
  }
  __syncthreads();
  const int lane = tid & 63, w = tid >> 6;
  const int wr = w >> 1, wc = w & 1;
  const int r15 = lane & 15;
  const int kb = (lane >> 4) * 16;
  const int ke = (lane >> 4) * 8;
  f32x4 acc2[4][3] = {};
  #pragma unroll
  for (int ks = 0; ks < 6; ks++){
    bf16x8 a[4];
    #pragma unroll
    for (int rt = 0; rt < 4; rt++){
      int row = wr*64 + rt*16 + r15;
      a[rt] = *(const bf16x8*)(smem + swzb(row*384 + ks*64 + kb, row));
    }
    #pragma unroll
    for (int ct = 0; ct < 3; ct++){
      int n = wc*48 + ct*16 + r15;
      bf16x8 b = *(const bf16x8*)(wt2 + n*192 + ks*32 + ke);
      #pragma unroll
      for (int rt = 0; rt < 4; rt++)
        acc2[rt][ct] = __builtin_amdgcn_mfma_f32_16x16x32_bf16(a[rt], b, acc2[rt][ct], 0, 0, 0);
    }
  }
  __syncthreads();
  #pragma unroll
  for (int ct = 0; ct < 3; ct++){
    int col = wc*48 + ct*16 + r15;
    float bs = b2[col];
    #pragma unroll
    for (int rt = 0; rt < 4; rt++){
      #pragma unroll
      for (int q = 0; q < 4; q++){
        int row = wr*64 + rt*16 + (lane >> 4)*4 + q;
        *(float*)(smem + row*392 + col*4) = alph[row] * lrelu(acc2[rt][ct][q] + bs);
      }
    }
  }
  __syncthreads();
  if (tid < 192){
    int hf = tid / 96;
    int c = tid - hf*96;
    int rbeg = hf*64, rend = rbeg + 64;
    float accv = 0.f;
    int cur = nid[rbeg];
    for (int r = rbeg; r < rend; r++){
      int n2 = nid[r];
      if (n2 != cur){ atomicAdd(num + cur*96 + c, accv); accv = 0.f; cur = n2; }
      accv += *(const float*)(smem + r*392 + c*4);
    }
    atomicAdd(num + cur*96 + c, accv);
  }
}

// the N rows with ind1=ind2=0 are identical: compute once, add 2048x
__global__ __launch_bounds__(256) void k_gcnode0(const float* __restrict__ h,
    const float* __restrict__ W1, const float* __restrict__ b1,
    const float* __restrict__ W2, const float* __restrict__ b2, float* __restrict__ num)
{
  __shared__ float in_s[192], h1_s[192];
  int t = threadIdx.x;
  if (t < 192) in_s[t] = h[t % 96];
  __syncthreads();
  if (t < 192){
    float s = b1[t];
    for (int k = 0; k < 192; k++) s += in_s[k] * W1[k*192 + t];
    h1_s[t] = lrelu(s);
  }
  __syncthreads();
  if (t < 96){
    float s = b2[t];
    for (int k = 0; k < 192; k++) s += h1_s[k] * W2[k*96 + t];
    num[t] += 2048.f * lrelu(s);
  }
}

__global__ __launch_bounds__(256) void k_hupd(const float* __restrict__ num, const float* __restrict__ den,
                                              float* __restrict__ h){
  int i = blockIdx.x * 256 + threadIdx.x;
  h[i] = num[i] / (den[i / 96] + 1e-8f);
}

// ---------------- final predictor v2: et = [efnn,ef]@W_cd (MFMA) ; out = sig(w2.lrelu(et+hp1[s]+hp2[d])) ----
__global__ __launch_bounds__(256) void k_final2(const float* __restrict__ hp1, const float* __restrict__ hp2,
    const int* __restrict__ ei, const u16* __restrict__ efnn, const float* __restrict__ efr,
    const float* __restrict__ es, const u16* __restrict__ enc,
    const float* __restrict__ enw2, const float* __restrict__ enb2, float* __restrict__ out)
{
  // LDS: [0,12288) A [64][192B swz] ; [12288,37120) et f32 [64][97] ; [37120) w2 f32[96] ; [37504) eix int[128]
  __shared__ __align__(16) char smem[38144];
  float* etb = (float*)(smem + 12288);
  float* w2s = (float*)(smem + 37120);
  int*   eix = (int*)  (smem + 37504);
  const int tid = threadIdx.x;
  const int e0 = blockIdx.x * 64;
  for (int j = tid; j < 768; j += 256){
    int r = j / 12, q = j - (j/12)*12;
    int e = e0 + r;
    bf16x8 v;
    if (q < 8){
      v = *(const bf16x8*)(efnn + (size_t)e*64 + q*8);
    } else if (q < 10){
      u16 pk[8];
      #pragma unroll
      for (int i = 0; i < 8; i++){
        int cc = (q - 8)*8 + i;           // ef col 0..15
        pk[i] = (cc < 12) ? f2bf((efr[(size_t)e*12 + cc] + 1e-4f) / es[cc]) : (u16)0;
      }
      v = *(bf16x8*)pk;
    } else {
      v = bf16x8{0,0,0,0,0,0,0,0};
    }
    *(bf16x8*)(smem + swzb(r*192 + q*16, r)) = v;
  }
  if (tid < 96) w2s[tid] = enw2[tid];
  if (tid < 64){ eix[2*tid] = ei[2*(e0+tid)]; eix[2*tid+1] = ei[2*(e0+tid)+1]; }
  __syncthreads();
  const int lane = tid & 63, w = tid >> 6;
  const int r15 = lane & 15;
  f32x4 acc[6] = {};
  tile_gemm_gb<6,3,192>(smem, w*16*192, enc, 96, lane, acc);
  #pragma unroll
  for (int ct = 0; ct < 6; ct++){
    int col = ct*16 + r15;
    #pragma unroll
    for (int q = 0; q < 4; q++){
      int row = w*16 + (lane >> 4)*4 + q;
      etb[row*97 + col] = acc[ct][q];
    }
  }
  __syncthreads();
  int r = tid >> 2, part = tid & 3;
  int s1 = eix[2*r], s2 = eix[2*r + 1];
  const float* p1 = hp1 + (size_t)s1*96 + part*24;
  const float* p2 = hp2 + (size_t)s2*96 + part*24;
  const float* et = etb + r*97 + part*24;
  const float* wz = w2s + part*24;
  float s = 0.f;
  #pragma unroll
  for (int i = 0; i < 24; i++){
    float v = et[i] + p1[i] + p2[i];
    s += lrelu(v) * wz[i];
  }
  s += __shfl_xor(s, 1); s += __shfl_xor(s, 2);
  if (part == 0) out[e0 + r] = 1.f / (1.f + __expf(-(s + enb2[0])));
}

// ---------------- host ----------------
extern "C" void kernel_launch(void* const* d_in, const int* in_sizes, int n_in,
                              void* d_out, int out_size, void* d_ws, size_t ws_size,
                              hipStream_t stream) {
  (void)in_sizes; (void)n_in; (void)out_size; (void)ws_size;
  const float* X      = (const float*)d_in[0];
  const float* EFR    = (const float*)d_in[1];
  const int*   EI     = (const int*)  d_in[2];
  const float* NS     = (const float*)d_in[3];
  const float* ES     = (const float*)d_in[4];
  const float* IN_W1  = (const float*)d_in[5];
  const float* IN_B1  = (const float*)d_in[6];
  const float* IN_W2  = (const float*)d_in[7];
  const float* IN_B2  = (const float*)d_in[8];
  const float* QKV_W  = (const float*)d_in[9];
  const float* QKV_B  = (const float*)d_in[10];
  const float* OUT_W  = (const float*)d_in[11];
  const float* OUT_B  = (const float*)d_in[12];
  const float* LN1S   = (const float*)d_in[13];
  const float* LN1B   = (const float*)d_in[14];
  const float* FFW1   = (const float*)d_in[15];
  const float* FFB1   = (const float*)d_in[16];
  const float* FFW2   = (const float*)d_in[17];
  const float* FFB2   = (const float*)d_in[18];
  const float* LN2S   = (const float*)d_in[19];
  const float* LN2B   = (const float*)d_in[20];
  const float* EIN_W1 = (const float*)d_in[21];
  const float* EIN_B1 = (const float*)d_in[22];
  const float* EIN_W2 = (const float*)d_in[23];
  const float* EIN_B2 = (const float*)d_in[24];
  const float* AD_W1  = (const float*)d_in[25];
  const float* AD_B1  = (const float*)d_in[26];
  const float* AD_W2  = (const float*)d_in[27];
  const float* AD_B2  = (const float*)d_in[28];
  const float* AR_W1  = (const float*)d_in[29];
  const float* AR_B1  = (const float*)d_in[30];
  const float* AR_W2  = (const float*)d_in[31];
  const float* AR_B2  = (const float*)d_in[32];
  const float* GC_W1  = (const float*)d_in[33];
  const float* GC_B1  = (const float*)d_in[34];
  const float* GC_W2  = (const float*)d_in[35];
  const float* GC_B2  = (const float*)d_in[36];
  const float* EN_W1  = (const float*)d_in[37];
  const float* EN_B1  = (const float*)d_in[38];
  const float* EN_W2  = (const float*)d_in[39];
  const float* EN_B2  = (const float*)d_in[40];

  char* ws = (char*)d_ws;
  u16*   pool   = (u16*)  (ws + WS_WT);
  u16*   efnn   = (u16*)  (ws + WS_EFNN);
  float* alpha  = (float*)(ws + WS_ALPHA);
  float* h      = (float*)(ws + WS_H);
  float* qkvb   = (float*)(ws + WS_QKV);
  float* obuf   = (float*)(ws + WS_OBUF);
  float* tmpA   = (float*)(ws + WS_TMPA);
  float* tmpB   = (float*)(ws + WS_TMPB);
  float* x1     = (float*)(ws + WS_X1);
  float* num    = (float*)(ws + WS_NUM);
  float* den    = (float*)(ws + WS_DEN);
  float* xs     = (float*)(ws + WS_XS);
  int2*  sidx   = (int2*) (ws + WS_SIDX);
  float* alphaS = (float*)(ws + WS_ALPS);
  int*   cnt    = (int*)  (ws + WS_CNT);
  int*   offs   = (int*)  (ws + WS_OFFS);
  float* P1     = (float*)(ws + WS_QKV);   // reuse (encoders done before gc)
  float* P2     = (float*)(ws + WS_TMPB);
  float* hp1    = (float*)(ws + WS_OBUF);
  float* hp2    = (float*)(ws + WS_TMPA);

  // ---- weight conversion jobs ----
  CvtJobs jb;
  int idx = 0, cum = 0;
  auto addjob = [&](const float* s, int K, int Nc, int Kp){
    jb.src[idx] = s; jb.K[idx] = K; jb.Nc[idx] = Nc; jb.Kp[idx] = Kp;
    jb.cum[idx] = cum; cum += Nc * Kp; idx++;
  };
  addjob(IN_W1, 19, 96, 32);
  addjob(IN_W2, 96, 96, 96);
  for (int l = 0; l < 3; l++) addjob(QKV_W + (size_t)l*96*288, 96, 288, 96);
  for (int l = 0; l < 3; l++) addjob(OUT_W + (size_t)l*96*96,  96, 96,  96);
  for (int l = 0; l < 3; l++) addjob(FFW1  + (size_t)l*96*192, 96, 192, 96);
  for (int l = 0; l < 3; l++) addjob(FFW2  + (size_t)l*192*96, 192, 96, 192);
  addjob(EIN_W1, 12, 64, 32);
  addjob(EIN_W2, 64, 64, 64);
  addjob(AD_W1,  64, 64, 64);
  addjob(AR_W1,  64, 64, 64);
  for (int i = 0; i < 2; i++){
    addjob(GC_W1 + (size_t)i*192*192,          96, 192, 96);   // top half
    addjob(GC_W1 + (size_t)i*192*192 + 96*192, 96, 192, 96);   // bottom half
  }
  for (int i = 0; i < 2; i++) addjob(GC_W2 + (size_t)i*192*96, 192, 96, 192);
  addjob(EN_W1,            96, 96, 96);   // W_a (h[src])
  addjob(EN_W1 + 96*96,    96, 96, 96);   // W_b (h[dst])
  addjob(EN_W1 + 192*96,   76, 96, 96);   // W_cd (efnn, ef)
  jb.cum[idx] = cum;   // == POOL_TOT

  k_cvt<<<(POOL_TOT + 255)/256, 256, 0, stream>>>(jb, pool);

  // ---- node embedding ----
  k_xscale<<<(NN*19 + 255)/256, 256, 0, stream>>>(X, NS, xs);
  k_gemm<6,1,1><<<32, 256, 0, stream>>>(xs, 19, pool + IN1T, IN_B1, tmpA);
  k_gemm<6,3,1><<<32, 256, 0, stream>>>(tmpA, 96, pool + IN2T, IN_B2, h);

  // ---- edge MLPs + attention weights ----
  k_edge<<<EE/64, 256, 0, stream>>>(EFR, ES, pool, EIN_B1, EIN_B2,
                                    AD_B1, AD_W2, AD_B2, AR_B1, AR_W2, AR_B2, efnn, alpha);

  // ---- destination sort + den ----
  (void)hipMemsetAsync(cnt, 0, NN*4, stream);
  k_hist<<<(2*EE)/256, 256, 0, stream>>>(EI, cnt);
  k_scan<<<1, 256, 0, stream>>>(cnt, offs);
  (void)hipMemsetAsync(cnt, 0, NN*4, stream);
  k_scatter<<<(2*EE)/256, 256, 0, stream>>>(EI, alpha, offs, cnt, sidx, alphaS);
  k_dens<<<NN/4, 256, 0, stream>>>(offs, alphaS, den);

  // ---- 3 encoder layers ----
  for (int l = 0; l < 3; l++){
    k_gemm<18,3,0><<<32, 256, 0, stream>>>(h, 96, pool + QKVT + l*27648, QKV_B + l*288, qkvb);
    k_attn2<<<384, 256, 0, stream>>>(qkvb, obuf);
    k_gemm<6,3,0><<<32, 256, 0, stream>>>(obuf, 96, pool + OUTT + l*9216, OUT_B + l*96, tmpA);
    k_ln<<<512, 256, 0, stream>>>(h, tmpA, LN1S + l*96, LN1B + l*96, x1);
    k_gemm<12,3,2><<<32, 256, 0, stream>>>(x1, 96, pool + FF1T + l*18432, FFB1 + l*192, tmpB);
    k_gemm<6,6,0><<<32, 256, 0, stream>>>(tmpB, 192, pool + FF2T + l*18432, FFB2 + l*96, tmpA);
    k_ln<<<512, 256, 0, stream>>>(x1, tmpA, LN2S + l*96, LN2B + l*96, h);
  }

  // ---- 2 graph-conv iterations ----
  for (int it = 0; it < 2; it++){
    k_gemm<12,3,0><<<32, 256, 0, stream>>>(h, 96, pool + GC1T + it*36864,         nullptr,       P1);
    k_gemm<12,3,0><<<32, 256, 0, stream>>>(h, 96, pool + GC1T + it*36864 + 18432, GC_B1 + it*192, P2);
    (void)hipMemsetAsync(num, 0, NN*96*4, stream);
    k_gc3<<<(2*EE)/128, 256, 0, stream>>>(P1, P2, sidx, alphaS,
        pool + GC2T + it*18432, GC_B2 + it*96, num);
    k_gcnode0<<<1, 256, 0, stream>>>(h, GC_W1 + (size_t)it*192*192, GC_B1 + it*192,
                                     GC_W2 + (size_t)it*192*96, GC_B2 + it*96, num);
    k_hupd<<<(NN*96)/256, 256, 0, stream>>>(num, den, h);
  }

  // ---- final predictor ----
  k_gemm<6,3,0><<<32, 256, 0, stream>>>(h, 96, pool + ENAT, nullptr, hp1);
  k_gemm<6,3,0><<<32, 256, 0, stream>>>(h, 96, pool + ENBT, EN_B1, hp2);
  k_final2<<<EE/64, 256, 0, stream>>>(hp1, hp2, EI, efnn, EFR, ES,
                                      pool + ENCT, EN_W2, EN_B2, (float*)d_out);
}